// Round 1
// 532.494 us; speedup vs baseline: 1.0275x; 1.0275x over previous
//
#include <hip/hip_runtime.h>
#include <hip/hip_bf16.h>
#include <cstdint>

#define DEV static __device__ __forceinline__

typedef unsigned short u16;
typedef unsigned int u32;
typedef __attribute__((ext_vector_type(8))) short short8;
typedef __attribute__((ext_vector_type(4))) float f32x4;

constexpr int Bn = 2, Ln = 2048, Dn = 2048, Hn = 16;
constexpr int Mrows = Bn * Ln;          // 4096
constexpr int CHK = 64, NCK = Ln / CHK; // chunk=64, 32 chunks/seq
constexpr int NCHUNKS = Bn * Hn * NCK;  // 1024

DEV float b2f(u16 s) { union { float f; u32 u; } x; x.u = ((u32)s) << 16; return x.f; }
DEV u16 f2b(float f) {
  union { float f; u32 u; } x; x.f = f; u32 u = x.u;
  return (u16)((u + 0x7fffu + ((u >> 16) & 1u)) >> 16);  // RNE
}

DEV void cp16(const void* g, void* l) {
  __builtin_amdgcn_global_load_lds(
      (const __attribute__((address_space(1))) u32*)(unsigned long long)(g),
      (__attribute__((address_space(3))) u32*)(unsigned long long)(l), 16, 0, 0);
}

DEV f32x4 mfma16(short8 a, short8 b, f32x4 c) {
  return __builtin_amdgcn_mfma_f32_16x16x32_bf16(a, b, c, 0, 0, 0);
}

// ---------------- fp32 -> bf16 elementwise convert ----------------
__global__ void k_cvt(const float* __restrict__ src, u16* __restrict__ dst, int n8) {
  int i = blockIdx.x * blockDim.x + threadIdx.x;
  if (i >= n8) return;
  const float4* s4 = (const float4*)(src + (size_t)i * 8);
  float4 a = s4[0], b = s4[1];
  u16 o[8] = {f2b(a.x), f2b(a.y), f2b(a.z), f2b(a.w), f2b(b.x), f2b(b.y), f2b(b.z), f2b(b.w)};
  *(short8*)(dst + (size_t)i * 8) = *(short8*)o;
}

// ---------------- transpose + downcast (fp32 weights -> bf16 B^T form) ----------------
struct TransArgs {
  const float* src[5]; u16* dst[5]; int rows[5]; int cols[5];
};
__global__ void k_trans(TransArgs t) {
  __shared__ u16 tile[32][33];
  int z = blockIdx.z;
  const float* src = t.src[z]; u16* dst = t.dst[z];
  int rows = t.rows[z], cols = t.cols[z];
  int r0 = blockIdx.y * 32, c0 = blockIdx.x * 32;
  if (r0 >= rows || c0 >= cols) return;
  int tx = threadIdx.x, ty = threadIdx.y;
  for (int i = ty; i < 32; i += 8) {
    int r = r0 + i, c = c0 + tx;
    if (r < rows && c < cols) tile[i][tx] = f2b(src[(size_t)r * cols + c]);
  }
  __syncthreads();
  for (int i = ty; i < 32; i += 8) {
    int r = c0 + i, c = r0 + tx;
    if (r < cols && c < rows) dst[(size_t)r * rows + c] = tile[tx][i];
  }
}

// ---------------- beta = sigmoid(hs @ Wb) for all heads, MFMA GEMV ----------------
__global__ __launch_bounds__(256) void k_beta(const u16* __restrict__ hs,
                                              const u16* __restrict__ WbT,
                                              float* __restrict__ beta_g) {
  int tid = threadIdx.x, wave = tid >> 6, lane = tid & 63, quad = lane >> 4, l15 = lane & 15;
  int tok0 = blockIdx.x * 64 + wave * 16;
  const u16* arow = hs + (size_t)(tok0 + l15) * Dn;   // A[m=l15][k]
  const u16* brow = WbT + (size_t)l15 * Dn;           // B[n=head=l15][k]
  f32x4 acc = {0.f, 0.f, 0.f, 0.f};
  for (int k = 0; k < Dn; k += 32) {
    short8 af = *(const short8*)&arow[k + quad * 8];
    short8 bf = *(const short8*)&brow[k + quad * 8];
    acc = mfma16(af, bf, acc);
  }
  int b = (blockIdx.x * 64) >> 11;
  int l = (blockIdx.x * 64 + wave * 16) & 2047;
#pragma unroll
  for (int r = 0; r < 4; r++) {
    beta_g[(size_t)(b * Hn + l15) * Ln + l + quad * 4 + r] = 1.f / (1.f + __expf(-acc[r]));
  }
}

// ---------------- 128x128-tile MFMA GEMM, C = act(A @ Bt^T) ----------------
struct GemmArgs {
  const u16* A; const u16* Bt; void* C; int epi;  // epi: 0 none, 1 silu
  int f32out;
  int M, N, K;
};
__global__ __launch_bounds__(256) void k_gemm(GemmArgs g) {
  __shared__ u16 As[128 * 64];
  __shared__ u16 Bs[128 * 64];
  const u16* A = g.A; const u16* Bt = g.Bt;
  int epi = g.epi;
  int K = g.K, N = g.N;
  int tid = threadIdx.x, wave = tid >> 6, lane = tid & 63;
  int quad = lane >> 4, l15 = lane & 15;
  int m0 = blockIdx.y * 128, n0 = blockIdx.x * 128;
  int wm = (wave >> 1) * 64, wn = (wave & 1) * 64;
  f32x4 acc[4][4];
#pragma unroll
  for (int i = 0; i < 4; i++)
#pragma unroll
    for (int j = 0; j < 4; j++) acc[i][j] = (f32x4){0.f, 0.f, 0.f, 0.f};
  const u16* Ag = A + (size_t)(m0 + wave * 32 + (lane >> 3)) * K + (lane & 7) * 8;
  const u16* Bg = Bt + (size_t)(n0 + wave * 32 + (lane >> 3)) * K + (lane & 7) * 8;
  u16* Al = &As[wave * 32 * 64];
  u16* Bl = &Bs[wave * 32 * 64];
  for (int k0 = 0; k0 < K; k0 += 64) {
#pragma unroll
    for (int t = 0; t < 4; t++) {
      cp16(Ag + k0 + t * 8 * K, Al + t * 8 * 64);
      cp16(Bg + k0 + t * 8 * K, Bl + t * 8 * 64);
    }
    __syncthreads();
#pragma unroll
    for (int kk = 0; kk < 64; kk += 32) {
      short8 af[4], bf[4];
#pragma unroll
      for (int i = 0; i < 4; i++) af[i] = *(const short8*)&As[(wm + i * 16 + l15) * 64 + kk + quad * 8];
#pragma unroll
      for (int i = 0; i < 4; i++) bf[i] = *(const short8*)&Bs[(wn + i * 16 + l15) * 64 + kk + quad * 8];
#pragma unroll
      for (int i = 0; i < 4; i++)
#pragma unroll
        for (int j = 0; j < 4; j++) acc[i][j] = mfma16(af[i], bf[j], acc[i][j]);
    }
    __syncthreads();
  }
#pragma unroll
  for (int i = 0; i < 4; i++)
#pragma unroll
    for (int j = 0; j < 4; j++) {
      int row = m0 + wm + i * 16 + quad * 4;
      int col = n0 + wn + j * 16 + l15;
#pragma unroll
      for (int r = 0; r < 4; r++) {
        float v = acc[i][j][r];
        if (epi == 1) v = v / (1.f + __expf(-v));  // silu
        if (g.f32out) ((float*)g.C)[(size_t)(row + r) * N + col] = v;
        else ((u16*)g.C)[(size_t)(row + r) * N + col] = f2b(v);
      }
    }
}

// ---------------- l2-normalize q,k rows of 128 (in place, bf16) ----------------
__global__ void k_l2(u16* qn, u16* kn) {
  int tid = threadIdx.x, wave = tid >> 6, lane = tid & 63;
  size_t row = (size_t)blockIdx.x * 4 + wave;  // (b*L+l)*16+h
  u16* p = (blockIdx.y ? kn : qn) + row * 128;
  u32 u = *(const u32*)&p[lane * 2];
  float x0 = b2f((u16)(u & 0xffff)), x1 = b2f((u16)(u >> 16));
  float ss = x0 * x0 + x1 * x1;
#pragma unroll
  for (int o = 32; o > 0; o >>= 1) ss += __shfl_xor(ss, o, 64);
  float sc = 1.f / fmaxf(sqrtf(ss), 1e-12f);
  if (blockIdx.y == 0) sc *= 0.08838834764831845f;  // dh^-0.5
  u32 outv = (u32)f2b(x0 * sc) | ((u32)f2b(x1 * sc) << 16);
  *(u32*)&p[lane * 2] = outv;
}

// ---------------- per-chunk precompute: Minv (Neumann), W2,U,G,KT ----------------
// ST=72: row stride 36 dwords (== 4 mod 32) puts ds_read_b128 fragment reads at
// the bank floor (8 lanes per 4-bank group). ST=80 (== 8 mod 32) was 2x floor.
constexpr int ST = 72;
// 4 LDS buffers (Br, Bc, M0, M1): T = B^2 staged through registers and written
// IN PLACE into Br/Bc -> LDS 61952 -> 37120 B -> 4 blocks/CU (was 2).
__global__ __launch_bounds__(256, 4) void k_pre(
    const float* __restrict__ beta_g,
    const u16* __restrict__ qn, const u16* __restrict__ kn, const u16* __restrict__ vn,
    u16* __restrict__ W2g, u16* __restrict__ Ug, u16* __restrict__ Gg, u16* __restrict__ KTg) {
  __shared__ float beta_s[64];
  __shared__ u16 mats[4 * 64 * ST];
  int gid = blockIdx.x;
  int c = gid & 31, h = (gid >> 5) & 15, b = gid >> 9;
  int tid = threadIdx.x;
  int l0 = c * 64;

  if (tid < 64) beta_s[tid] = beta_g[(size_t)(b * Hn + h) * Ln + l0 + tid];
  __syncthreads();

  int wave = tid >> 6, lane = tid & 63, quad = lane >> 4, l15 = lane & 15;
  u16 *Br = mats, *Bc = mats + 64 * ST, *M0 = mats + 2 * 64 * ST, *M1 = mats + 3 * 64 * ST;

  // P1: A_full = K K^T (MFMA), G = tril(Q K^T); build B=-strict_tril(diag(beta)A), M=I+B
  {
    const u16* krowB = kn + (size_t)(b * Ln + l0 + wave * 16 + l15) * Dn + h * 128;
    short8 bfr[4];
#pragma unroll
    for (int s = 0; s < 4; s++) bfr[s] = *(const short8*)&krowB[quad * 8 + 32 * s];
#pragma unroll
    for (int mt = 0; mt < 4; ++mt) {
      const u16* arow_k = kn + (size_t)(b * Ln + l0 + mt * 16 + l15) * Dn + h * 128;
      const u16* arow_q = qn + (size_t)(b * Ln + l0 + mt * 16 + l15) * Dn + h * 128;
      f32x4 accA = {0.f, 0.f, 0.f, 0.f}, accG = {0.f, 0.f, 0.f, 0.f};
#pragma unroll
      for (int s = 0; s < 4; s++) {
        short8 ak = *(const short8*)&arow_k[quad * 8 + 32 * s];
        short8 aq = *(const short8*)&arow_q[quad * 8 + 32 * s];
        accA = mfma16(ak, bfr[s], accA);
        accG = mfma16(aq, bfr[s], accG);
      }
      int t = wave * 16 + l15;
#pragma unroll
      for (int r = 0; r < 4; r++) {
        int i = mt * 16 + quad * 4 + r;
        u16 nb = f2b((t < i) ? -beta_s[i] * accA[r] : 0.f);
        Br[i * ST + t] = nb;
        Bc[t * ST + i] = nb;
        M0[i * ST + t] = (t == i) ? f2b(1.f) : nb;
        Gg[(size_t)gid * 4096 + (size_t)i * 64 + t] = f2b((t <= i) ? accG[r] : 0.f);
      }
    }
  }
  __syncthreads();

  // P2: Minv = (I+B)(I+B^2)(I+B^4)(I+B^8)(I+B^16)(I+B^32)
  // B strictly lower-tril => B^p block (mt,w) nonzero iff (mt-w)*16+15 >= p.
  // Skip thresholds (wave-uniform): output B^{2p}: thrT = {0,0,0,1,2};
  // previously-stored B^p (write skip): thrI = {0,0,0,0,1}. M-update product
  // M@T block nonzero iff mt-w >= thrT (M is unit-lower-triangular).
  u16 *Mc = M0, *Mn = M1;
#pragma unroll
  for (int it = 0; it < 5; ++it) {
    const int tT = (it < 3) ? 0 : ((it == 3) ? 1 : 2);
    const int tI = (it < 4) ? 0 : 1;
    // stage all B reads (bb cols + af rows) before overwriting Br/Bc
    short8 bb[2];
#pragma unroll
    for (int s = 0; s < 2; s++) bb[s] = *(const short8*)&Bc[(wave * 16 + l15) * ST + quad * 8 + 32 * s];
    f32x4 accT[4];
#pragma unroll
    for (int mt = 0; mt < 4; mt++) {
      accT[mt] = (f32x4){0.f, 0.f, 0.f, 0.f};
      if (mt - wave >= tT) {
#pragma unroll
        for (int s = 0; s < 2; s++) {
          short8 af = *(const short8*)&Br[(mt * 16 + l15) * ST + quad * 8 + 32 * s];
          accT[mt] = mfma16(af, bb[s], accT[mt]);
        }
      }
    }
    __syncthreads();  // all lanes done reading Br/Bc -> safe to overwrite
    // write T = B^{2p} in place (blocks that were already zero stay untouched)
#pragma unroll
    for (int mt = 0; mt < 4; mt++) {
      if (mt - wave >= tI) {
#pragma unroll
        for (int r = 0; r < 4; r++) {
          int i = mt * 16 + quad * 4 + r, t = wave * 16 + l15;
          u16 v = f2b(accT[mt][r]);
          Br[i * ST + t] = v;
          Bc[t * ST + i] = v;
        }
      }
    }
    __syncthreads();  // T visible
    // M <- M (I + T)
    short8 tb[2];
#pragma unroll
    for (int s = 0; s < 2; s++) tb[s] = *(const short8*)&Bc[(wave * 16 + l15) * ST + quad * 8 + 32 * s];
#pragma unroll
    for (int mt = 0; mt < 4; mt++) {
      if (mt - wave >= tT) {
        f32x4 a;
#pragma unroll
        for (int r = 0; r < 4; r++) a[r] = b2f(Mc[(mt * 16 + quad * 4 + r) * ST + wave * 16 + l15]);
#pragma unroll
        for (int s = 0; s < 2; s++) {
          short8 af = *(const short8*)&Mc[(mt * 16 + l15) * ST + quad * 8 + 32 * s];
          a = mfma16(af, tb[s], a);
        }
#pragma unroll
        for (int r = 0; r < 4; r++) Mn[(mt * 16 + quad * 4 + r) * ST + wave * 16 + l15] = f2b(a[r]);
      } else {
        // product block statically zero: raw copy
#pragma unroll
        for (int r = 0; r < 4; r++)
          Mn[(mt * 16 + quad * 4 + r) * ST + wave * 16 + l15] =
              Mc[(mt * 16 + quad * 4 + r) * ST + wave * 16 + l15];
      }
    }
    u16* tmp = Mc; Mc = Mn; Mn = tmp;
    // NOTE: no barrier needed here: next iteration's first barrier orders the
    // Mn writes / tb reads against the next in-place overwrite of Br/Bc.
  }
  __syncthreads();  // drain last M-update (tb/Mc reads) before XT reuses Br/Bc

  // P3: W2 = Minv (beta.K), U = Minv (beta.V); also KT (unscaled) to global
  u16* XT = mats;  // scratch slots 0-1 (Br,Bc); Mc lives in slot 3 after 5 swaps
  for (int pass = 0; pass < 2; ++pass) {
    const u16* src = pass ? vn : kn;
    for (int idx = tid; idx < 64 * 128; idx += 256) {
      int t = idx >> 7, dk = idx & 127;
      float v = b2f(src[(size_t)(b * Ln + l0 + t) * Dn + h * 128 + dk]);
      XT[dk * ST + t] = f2b(v * beta_s[t]);
      if (pass == 0) KTg[(size_t)gid * 8192 + (size_t)dk * 64 + t] = f2b(v);
    }
    __syncthreads();
    u16* dst = pass ? Ug : W2g;
#pragma unroll
    for (int half = 0; half < 2; ++half) {
      int nt = wave + half * 4;
      short8 bx[2];
#pragma unroll
      for (int s = 0; s < 2; s++) bx[s] = *(const short8*)&XT[(nt * 16 + l15) * ST + quad * 8 + 32 * s];
#pragma unroll
      for (int mt = 0; mt < 4; mt++) {
        f32x4 a = {0.f, 0.f, 0.f, 0.f};
#pragma unroll
        for (int s = 0; s < 2; s++) {
          short8 af = *(const short8*)&Mc[(mt * 16 + l15) * ST + quad * 8 + 32 * s];
          a = mfma16(af, bx[s], a);
        }
#pragma unroll
        for (int r = 0; r < 4; r++)
          dst[(size_t)gid * 8192 + (size_t)(mt * 16 + quad * 4 + r) * 128 + nt * 16 + l15] = f2b(a[r]);
      }
    }
    __syncthreads();
  }
}

// ---------------- sequential chunk scan (per b,h and 16-wide v-slice) ----------------
struct Frg { short8 w2[4], qf[4], gf[2], k0[2], k1[2]; float u[4]; };

__global__ __launch_bounds__(256) void k_scan(
    const u16* __restrict__ qn, const u16* __restrict__ W2g, const u16* __restrict__ Ug,
    const u16* __restrict__ Gg, const u16* __restrict__ KTg, u16* __restrict__ Og) {
  constexpr int SST = 136, DST = 104;
  __shared__ u16 Sb[16 * SST];  // S^T slice, bf16 shadow: [v][dk]
  __shared__ u16 Db[16 * DST];  // Delta^T slice: [v][t]
  int bh = blockIdx.x, sl = blockIdx.y;
  int b = bh >> 4, h = bh & 15, c0 = sl * 16;
  int tid = threadIdx.x, wave = tid >> 6, lane = tid & 63, quad = lane >> 4, l15 = lane & 15;
  for (int i = tid; i < 16 * SST; i += 256) Sb[i] = 0;
  f32x4 accS0 = {0.f, 0.f, 0.f, 0.f}, accS1 = {0.f, 0.f, 0.f, 0.f};  // fp32 master state
  __syncthreads();

  auto load_frags = [&](Frg& F, int ci) {
    size_t ck = (size_t)bh * NCK + ci;
    const u16* w2row = W2g + ck * 8192 + (size_t)(wave * 16 + l15) * 128;
    const u16* qrow = qn + (size_t)(b * Ln + ci * 64 + wave * 16 + l15) * Dn + h * 128;
#pragma unroll
    for (int s = 0; s < 4; s++) {
      F.w2[s] = *(const short8*)&w2row[quad * 8 + 32 * s];
      F.qf[s] = *(const short8*)&qrow[quad * 8 + 32 * s];
    }
    const u16* grow = Gg + ck * 4096 + (size_t)(wave * 16 + l15) * 64;
    const u16* kt0 = KTg + ck * 8192 + (size_t)(wave * 16 + l15) * 64;
    const u16* kt1 = KTg + ck * 8192 + (size_t)((wave + 4) * 16 + l15) * 64;
#pragma unroll
    for (int s = 0; s < 2; s++) {
      F.gf[s] = *(const short8*)&grow[quad * 8 + 32 * s];
      F.k0[s] = *(const short8*)&kt0[quad * 8 + 32 * s];
      F.k1[s] = *(const short8*)&kt1[quad * 8 + 32 * s];
    }
    const u16* urow = Ug + ck * 8192 + (size_t)(wave * 16 + quad * 4) * 128 + c0 + l15;
#pragma unroll
    for (int r = 0; r < 4; r++) F.u[r] = b2f(urow[(size_t)r * 128]);
  };

  auto compute = [&](const Frg& F, int ci) {
    f32x4 accT = {0.f, 0.f, 0.f, 0.f}, accO = {0.f, 0.f, 0.f, 0.f};
#pragma unroll
    for (int s = 0; s < 4; s++) {
      short8 sf = *(const short8*)&Sb[l15 * SST + quad * 8 + 32 * s];
      accT = mfma16(F.w2[s], sf, accT);   // W2 @ S0
      accO = mfma16(F.qf[s], sf, accO);   // Q @ S0
    }
#pragma unroll
    for (int r = 0; r < 4; r++) {
      float d = F.u[r] - accT[r];         // Delta = U - W2@S0
      Db[l15 * DST + wave * 16 + quad * 4 + r] = f2b(d);
    }
    __syncthreads();
#pragma unroll
    for (int s = 0; s < 2; s++) {
      short8 df = *(const short8*)&Db[l15 * DST + quad * 8 + 32 * s];
      accO = mfma16(F.gf[s], df, accO);   // O += tril(QK^T) @ Delta
      accS0 = mfma16(F.k0[s], df, accS0); // S += K^T @ Delta
      accS1 = mfma16(F.k1[s], df, accS1);
    }
    u16* orow = Og + (size_t)(b * Ln + ci * 64 + wave * 16 + quad * 4) * Dn + h * 128 + c0 + l15;
#pragma unroll
    for (int r = 0; r < 4; r++) orow[(size_t)r * Dn] = f2b(accO[r]);
#pragma unroll
    for (int r = 0; r < 4; r++) {
      Sb[l15 * SST + wave * 16 + quad * 4 + r] = f2b(accS0[r]);
      Sb[l15 * SST + (wave + 4) * 16 + quad * 4 + r] = f2b(accS1[r]);
    }
    __syncthreads();
  };

  Frg FA, FB;
  load_frags(FA, 0);
  for (int ci = 0; ci < NCK; ci += 2) {
    load_frags(FB, ci + 1);
    compute(FA, ci);
    if (ci + 2 < NCK) load_frags(FA, ci + 2);
    compute(FB, ci + 1);
  }
}

// ---------------- RMSNorm over head dim (fp32 weight) ----------------
__global__ void k_rms(const u16* __restrict__ Og, const float* __restrict__ w, u16* __restrict__ out) {
  int tid = threadIdx.x, wave = tid >> 6, lane = tid & 63;
  size_t row = (size_t)blockIdx.x * 4 + wave;
  const u16* p = Og + row * 128;
  u32 u = *(const u32*)&p[lane * 2];
  float x0 = b2f((u16)(u & 0xffff)), x1 = b2f((u16)(u >> 16));
  float ss = x0 * x0 + x1 * x1;
#pragma unroll
  for (int o = 32; o > 0; o >>= 1) ss += __shfl_xor(ss, o, 64);
  float sc = rsqrtf(ss * (1.f / 128.f) + 1e-5f);
  float w0 = w[lane * 2], w1 = w[lane * 2 + 1];
  u32 o2 = (u32)f2b(x0 * sc * w0) | ((u32)f2b(x1 * sc * w1) << 16);
  *(u32*)&out[row * 128 + lane * 2] = o2;
}

// ---------------- host ----------------
extern "C" void kernel_launch(void* const* d_in, const int* in_sizes, int n_in,
                              void* d_out, int out_size, void* d_ws, size_t ws_size,
                              hipStream_t stream) {
  (void)in_sizes; (void)n_in; (void)out_size; (void)ws_size;
  const float* hs_f = (const float*)d_in[0];
  const float* Wq = (const float*)d_in[1];
  const float* Wk = (const float*)d_in[2];
  const float* Wv = (const float*)d_in[3];
  const float* Wb = (const float*)d_in[4];
  const float* onw = (const float*)d_in[5];
  const float* Wo = (const float*)d_in[6];

  char* ws = (char*)d_ws;
  size_t off = 0;
  auto alloc = [&](size_t bytes) -> void* {
    void* p = ws + off;
    off += (bytes + 255) & ~(size_t)255;
    return p;
  };
  const size_t WB = (size_t)2048 * 2048 * 2;
  const size_t XB = (size_t)4096 * 2048 * 2;
  u16* WqT = (u16*)alloc(WB);
  u16* WkT = (u16*)alloc(WB);
  u16* WvT = (u16*)alloc(WB);
  u16* WoT = (u16*)alloc(WB);
  u16* WbT = (u16*)alloc((size_t)16 * 2048 * 2);
  u16* hsb = (u16*)alloc(XB);
  u16* qn  = (u16*)alloc(XB);
  u16* kn  = (u16*)alloc(XB);
  u16* vn  = (u16*)alloc(XB);             // reused as O after precompute
  u16* W2g = (u16*)alloc((size_t)NCHUNKS * 8192 * 2);
  u16* Ug  = (u16*)alloc((size_t)NCHUNKS * 8192 * 2);
  u16* Gg  = (u16*)alloc((size_t)NCHUNKS * 4096 * 2);
  u16* KTg = (u16*)alloc((size_t)NCHUNKS * 8192 * 2);
  float* beta_g = (float*)alloc((size_t)Bn * Hn * Ln * 4);
  u16* Og = vn;       // v dead after precompute
  u16* onorm = qn;    // q dead after scan

  // 0) downcast hidden_states
  hipLaunchKernelGGL(k_cvt, dim3(Mrows * Dn / 8 / 256), dim3(256), 0, stream, hs_f, hsb, Mrows * Dn / 8);

  // 1) transposes + downcast
  TransArgs ta;
  ta.src[0] = Wq; ta.dst[0] = WqT; ta.rows[0] = 2048; ta.cols[0] = 2048;
  ta.src[1] = Wk; ta.dst[1] = WkT; ta.rows[1] = 2048; ta.cols[1] = 2048;
  ta.src[2] = Wv; ta.dst[2] = WvT; ta.rows[2] = 2048; ta.cols[2] = 2048;
  ta.src[3] = Wo; ta.dst[3] = WoT; ta.rows[3] = 2048; ta.cols[3] = 2048;
  ta.src[4] = Wb; ta.dst[4] = WbT; ta.rows[4] = 2048; ta.cols[4] = 16;
  hipLaunchKernelGGL(k_trans, dim3(64, 64, 5), dim3(32, 8), 0, stream, ta);

  // 1b) beta for all heads (reads hs once)
  hipLaunchKernelGGL(k_beta, dim3(Mrows / 64), dim3(256), 0, stream, hsb, WbT, beta_g);

  // 2) q/k/v projections (bf16 out), 3 separate dispatches for profiling clarity
  {
    const u16* Bts[3] = {WqT, WkT, WvT};
    u16* Cs[3] = {qn, kn, vn};
    int epis[3] = {0, 0, 1};
    for (int z = 0; z < 3; z++) {
      GemmArgs gq;
      gq.A = hsb; gq.Bt = Bts[z]; gq.C = Cs[z]; gq.epi = epis[z];
      gq.f32out = 0; gq.M = Mrows; gq.N = 2048; gq.K = 2048;
      hipLaunchKernelGGL(k_gemm, dim3(16, 32), dim3(256), 0, stream, gq);
    }
  }

  // 3) l2 normalize q (with dh^-0.5) and k
  hipLaunchKernelGGL(k_l2, dim3(16384, 2), dim3(256), 0, stream, qn, kn);

  // 4) chunk precompute
  hipLaunchKernelGGL(k_pre, dim3(NCHUNKS), dim3(256), 0, stream,
                     beta_g, qn, kn, vn, W2g, Ug, Gg, KTg);

  // 5) sequential scan
  hipLaunchKernelGGL(k_scan, dim3(32, 8), dim3(256), 0, stream,
                     qn, W2g, Ug, Gg, KTg, Og);

  // 6) RMSNorm
  hipLaunchKernelGGL(k_rms, dim3(16384), dim3(256), 0, stream, Og, onw, onorm);

  // 7) output projection (fp32 out -> d_out)
  GemmArgs go;
  go.A = onorm; go.Bt = WoT; go.C = d_out; go.epi = 0;
  go.f32out = 1; go.M = Mrows; go.N = 2048; go.K = 2048;
  hipLaunchKernelGGL(k_gemm, dim3(16, 32), dim3(256), 0, stream, go);
}

// Round 2
// 510.036 us; speedup vs baseline: 1.0727x; 1.0440x over previous
//
#include <hip/hip_runtime.h>
#include <hip/hip_bf16.h>
#include <cstdint>

#define DEV static __device__ __forceinline__

typedef unsigned short u16;
typedef unsigned int u32;
typedef __attribute__((ext_vector_type(8))) short short8;
typedef __attribute__((ext_vector_type(4))) float f32x4;

constexpr int Bn = 2, Ln = 2048, Dn = 2048, Hn = 16;
constexpr int Mrows = Bn * Ln;          // 4096
constexpr int CHK = 64, NCK = Ln / CHK; // chunk=64, 32 chunks/seq
constexpr int NCHUNKS = Bn * Hn * NCK;  // 1024

DEV float b2f(u16 s) { union { float f; u32 u; } x; x.u = ((u32)s) << 16; return x.f; }
DEV u16 f2b(float f) {
  union { float f; u32 u; } x; x.f = f; u32 u = x.u;
  return (u16)((u + 0x7fffu + ((u >> 16) & 1u)) >> 16);  // RNE
}

DEV void cp16(const void* g, void* l) {
  __builtin_amdgcn_global_load_lds(
      (const __attribute__((address_space(1))) u32*)(unsigned long long)(g),
      (__attribute__((address_space(3))) u32*)(unsigned long long)(l), 16, 0, 0);
}

DEV f32x4 mfma16(short8 a, short8 b, f32x4 c) {
  return __builtin_amdgcn_mfma_f32_16x16x32_bf16(a, b, c, 0, 0, 0);
}

// ---------------- fp32 -> bf16 elementwise convert ----------------
__global__ void k_cvt(const float* __restrict__ src, u16* __restrict__ dst, int n8) {
  int i = blockIdx.x * blockDim.x + threadIdx.x;
  if (i >= n8) return;
  const float4* s4 = (const float4*)(src + (size_t)i * 8);
  float4 a = s4[0], b = s4[1];
  u16 o[8] = {f2b(a.x), f2b(a.y), f2b(a.z), f2b(a.w), f2b(b.x), f2b(b.y), f2b(b.z), f2b(b.w)};
  *(short8*)(dst + (size_t)i * 8) = *(short8*)o;
}

// ---------------- transpose + downcast (fp32 weights -> bf16 B^T form) ----------------
struct TransArgs {
  const float* src[5]; u16* dst[5]; int rows[5]; int cols[5];
};
__global__ void k_trans(TransArgs t) {
  __shared__ u16 tile[32][33];
  int z = blockIdx.z;
  const float* src = t.src[z]; u16* dst = t.dst[z];
  int rows = t.rows[z], cols = t.cols[z];
  int r0 = blockIdx.y * 32, c0 = blockIdx.x * 32;
  if (r0 >= rows || c0 >= cols) return;
  int tx = threadIdx.x, ty = threadIdx.y;
  for (int i = ty; i < 32; i += 8) {
    int r = r0 + i, c = c0 + tx;
    if (r < rows && c < cols) tile[i][tx] = f2b(src[(size_t)r * cols + c]);
  }
  __syncthreads();
  for (int i = ty; i < 32; i += 8) {
    int r = c0 + i, c = r0 + tx;
    if (r < cols && c < rows) dst[(size_t)r * rows + c] = tile[tx][i];
  }
}

// ---------------- beta = sigmoid(hs @ Wb) for all heads, MFMA GEMV ----------------
__global__ __launch_bounds__(256) void k_beta(const u16* __restrict__ hs,
                                              const u16* __restrict__ WbT,
                                              float* __restrict__ beta_g) {
  int tid = threadIdx.x, wave = tid >> 6, lane = tid & 63, quad = lane >> 4, l15 = lane & 15;
  int tok0 = blockIdx.x * 64 + wave * 16;
  const u16* arow = hs + (size_t)(tok0 + l15) * Dn;   // A[m=l15][k]
  const u16* brow = WbT + (size_t)l15 * Dn;           // B[n=head=l15][k]
  f32x4 acc = {0.f, 0.f, 0.f, 0.f};
  for (int k = 0; k < Dn; k += 32) {
    short8 af = *(const short8*)&arow[k + quad * 8];
    short8 bf = *(const short8*)&brow[k + quad * 8];
    acc = mfma16(af, bf, acc);
  }
  int b = (blockIdx.x * 64) >> 11;
  int l = (blockIdx.x * 64 + wave * 16) & 2047;
#pragma unroll
  for (int r = 0; r < 4; r++) {
    beta_g[(size_t)(b * Hn + l15) * Ln + l + quad * 4 + r] = 1.f / (1.f + __expf(-acc[r]));
  }
}

// ---------------- 128x128-tile MFMA GEMM, C = act(A @ Bt^T) ----------------
struct GemmArgs {
  const u16* A; const u16* Bt; void* C; int epi;  // epi: 0 none, 1 silu
  int f32out;
  int M, N, K;
};
__global__ __launch_bounds__(256) void k_gemm(GemmArgs g) {
  __shared__ u16 As[128 * 64];
  __shared__ u16 Bs[128 * 64];
  const u16* A = g.A; const u16* Bt = g.Bt;
  int epi = g.epi;
  int K = g.K, N = g.N;
  int tid = threadIdx.x, wave = tid >> 6, lane = tid & 63;
  int quad = lane >> 4, l15 = lane & 15;
  int m0 = blockIdx.y * 128, n0 = blockIdx.x * 128;
  int wm = (wave >> 1) * 64, wn = (wave & 1) * 64;
  f32x4 acc[4][4];
#pragma unroll
  for (int i = 0; i < 4; i++)
#pragma unroll
    for (int j = 0; j < 4; j++) acc[i][j] = (f32x4){0.f, 0.f, 0.f, 0.f};
  const u16* Ag = A + (size_t)(m0 + wave * 32 + (lane >> 3)) * K + (lane & 7) * 8;
  const u16* Bg = Bt + (size_t)(n0 + wave * 32 + (lane >> 3)) * K + (lane & 7) * 8;
  u16* Al = &As[wave * 32 * 64];
  u16* Bl = &Bs[wave * 32 * 64];
  for (int k0 = 0; k0 < K; k0 += 64) {
#pragma unroll
    for (int t = 0; t < 4; t++) {
      cp16(Ag + k0 + t * 8 * K, Al + t * 8 * 64);
      cp16(Bg + k0 + t * 8 * K, Bl + t * 8 * 64);
    }
    __syncthreads();
#pragma unroll
    for (int kk = 0; kk < 64; kk += 32) {
      short8 af[4], bf[4];
#pragma unroll
      for (int i = 0; i < 4; i++) af[i] = *(const short8*)&As[(wm + i * 16 + l15) * 64 + kk + quad * 8];
#pragma unroll
      for (int i = 0; i < 4; i++) bf[i] = *(const short8*)&Bs[(wn + i * 16 + l15) * 64 + kk + quad * 8];
#pragma unroll
      for (int i = 0; i < 4; i++)
#pragma unroll
        for (int j = 0; j < 4; j++) acc[i][j] = mfma16(af[i], bf[j], acc[i][j]);
    }
    __syncthreads();
  }
#pragma unroll
  for (int i = 0; i < 4; i++)
#pragma unroll
    for (int j = 0; j < 4; j++) {
      int row = m0 + wm + i * 16 + quad * 4;
      int col = n0 + wn + j * 16 + l15;
#pragma unroll
      for (int r = 0; r < 4; r++) {
        float v = acc[i][j][r];
        if (epi == 1) v = v / (1.f + __expf(-v));  // silu
        if (g.f32out) ((float*)g.C)[(size_t)(row + r) * N + col] = v;
        else ((u16*)g.C)[(size_t)(row + r) * N + col] = f2b(v);
      }
    }
}

// ---------------- 256x256x64 8-wave GEMM, counted vmcnt pipeline (T2+T3+T4+T5) ----
// Fused QKV: A [4096][2048], Bt [6144][2048] (WqT|WkT|WvT contiguous),
// C = qn base; z = nf>>11 selects {qn,kn,vn}; silu on z==2.
struct Gemm2Args { const u16* A; const u16* Bt; u16* C; int K; };

DEV const short8* fragp(const u16* buf, int row, int colb) {
  // st_16x32 swizzle on read: physical = row*128 + (colb ^ ((row&4)<<3))
  return (const short8*)((const char*)buf + row * 128 + (colb ^ ((row & 4) << 3)));
}

__global__ __launch_bounds__(512, 2) void k_gemm2(Gemm2Args g) {
  __shared__ u16 lds[2][2][256 * 64];  // [buf][A/B][256 rows x 64 cols] = 128 KiB
  const int K = g.K, NT = K / 64;
  const size_t Kb = (size_t)K * 2;
  int tid = threadIdx.x, wave = tid >> 6, lane = tid & 63;
  int quad = lane >> 4, l15 = lane & 15;
  int wm = wave >> 2, wn = wave & 3;  // 2M x 4N wave grid

  // XCD-aware bijective swizzle (384 % 8 == 0), then n-fast decompose 16x24
  int bid = blockIdx.x;
  int wg = (bid & 7) * 48 + (bid >> 3);
  int by = wg / 24, bx = wg - by * 24;
  int m0 = by * 256, n0f = bx * 256;

  // per-lane pre-swizzled global source addresses (inverse st_16x32 on source)
  const char* gA0 = (const char*)g.A + (size_t)(m0 + wave * 8 + (lane >> 3)) * Kb +
                    (((lane & 7) * 16) ^ (lane & 32));
  const char* gB0 = (const char*)g.Bt + (size_t)(n0f + wave * 8 + (lane >> 3)) * Kb +
                    (((lane & 7) * 16) ^ (lane & 32));

  auto stage = [&](int buf, int t) {
    const char* pa = gA0 + (size_t)t * 128;
    const char* pb = gB0 + (size_t)t * 128;
    u16* la = &lds[buf][0][wave * 512];
    u16* lb = &lds[buf][1][wave * 512];
#pragma unroll
    for (int s = 0; s < 4; s++) {
      cp16(pa + (size_t)s * 64 * Kb, la + s * 4096);
      cp16(pb + (size_t)s * 64 * Kb, lb + s * 4096);
    }
  };

  f32x4 acc0[4][4], acc1[4][4];
#pragma unroll
  for (int i = 0; i < 4; i++)
#pragma unroll
    for (int j = 0; j < 4; j++) {
      acc0[i][j] = (f32x4){0.f, 0.f, 0.f, 0.f};
      acc1[i][j] = (f32x4){0.f, 0.f, 0.f, 0.f};
    }

  int ra = wm * 128 + l15;  // A frag row base (+mq*64 + i*16)
  int rb = wn * 64 + l15;   // B frag row base (+j*16)
  int cb0 = quad * 16;      // kk=0 col bytes
  int cb1 = 64 + quad * 16; // kk=32 col bytes

  // prologue: 2 K-tiles in flight (16 loads/thread)
  stage(0, 0);
  stage(1, 1);

  for (int t = 0; t < NT; ++t) {
    int cur = t & 1;
    if (t == NT - 1) {
      asm volatile("s_waitcnt vmcnt(0)" ::: "memory");
    } else {
      asm volatile("s_waitcnt vmcnt(8)" ::: "memory");  // tile t landed; t+1 in flight
    }
    __builtin_amdgcn_s_barrier();
    __builtin_amdgcn_sched_barrier(0);
    const u16* bA = &lds[cur][0][0];
    const u16* bB = &lds[cur][1][0];

    short8 A0[4], A1[4], B0[4];
    // ---- kk = 0 ----
#pragma unroll
    for (int i = 0; i < 4; i++) A0[i] = *fragp(bA, ra + i * 16, cb0);
#pragma unroll
    for (int j = 0; j < 4; j++) B0[j] = *fragp(bB, rb + j * 16, cb0);
    __builtin_amdgcn_s_setprio(1);
#pragma unroll
    for (int i = 0; i < 4; i++)
#pragma unroll
      for (int j = 0; j < 4; j++) acc0[i][j] = mfma16(A0[i], B0[j], acc0[i][j]);
    __builtin_amdgcn_s_setprio(0);
#pragma unroll
    for (int i = 0; i < 4; i++) A1[i] = *fragp(bA, ra + 64 + i * 16, cb0);
    __builtin_amdgcn_s_setprio(1);
#pragma unroll
    for (int i = 0; i < 4; i++)
#pragma unroll
      for (int j = 0; j < 4; j++) acc1[i][j] = mfma16(A1[i], B0[j], acc1[i][j]);
    __builtin_amdgcn_s_setprio(0);
    // ---- kk = 32 ----
#pragma unroll
    for (int i = 0; i < 4; i++) A0[i] = *fragp(bA, ra + i * 16, cb1);
#pragma unroll
    for (int j = 0; j < 4; j++) B0[j] = *fragp(bB, rb + j * 16, cb1);
    __builtin_amdgcn_s_setprio(1);
#pragma unroll
    for (int i = 0; i < 4; i++)
#pragma unroll
      for (int j = 0; j < 4; j++) acc0[i][j] = mfma16(A0[i], B0[j], acc0[i][j]);
    __builtin_amdgcn_s_setprio(0);
#pragma unroll
    for (int i = 0; i < 4; i++) A1[i] = *fragp(bA, ra + 64 + i * 16, cb1);
    __builtin_amdgcn_s_setprio(1);
#pragma unroll
    for (int i = 0; i < 4; i++)
#pragma unroll
      for (int j = 0; j < 4; j++) acc1[i][j] = mfma16(A1[i], B0[j], acc1[i][j]);
    __builtin_amdgcn_s_setprio(0);

    __builtin_amdgcn_s_barrier();  // all waves done reading buf[cur]
    if (t + 2 < NT) stage(cur, t + 2);
  }

  // epilogue
  int zq = n0f >> 11;
  u16* Cz = g.C + (size_t)zq * ((size_t)Mrows * 2048);
  int colB = (n0f & 2047) + wn * 64;
  int rowB = m0 + wm * 128;
#pragma unroll
  for (int mq = 0; mq < 2; mq++) {
#pragma unroll
    for (int i = 0; i < 4; i++)
#pragma unroll
      for (int j = 0; j < 4; j++) {
        f32x4 a = mq ? acc1[i][j] : acc0[i][j];
        int row = rowB + mq * 64 + i * 16 + quad * 4;
        int col = colB + j * 16 + l15;
#pragma unroll
        for (int r = 0; r < 4; r++) {
          float v = a[r];
          if (zq == 2) v = v / (1.f + __expf(-v));  // silu (v-projection)
          Cz[(size_t)(row + r) * 2048 + col] = f2b(v);
        }
      }
  }
}

// ---------------- l2-normalize q,k rows of 128 (in place, bf16) ----------------
__global__ void k_l2(u16* qn, u16* kn) {
  int tid = threadIdx.x, wave = tid >> 6, lane = tid & 63;
  size_t row = (size_t)blockIdx.x * 4 + wave;  // (b*L+l)*16+h
  u16* p = (blockIdx.y ? kn : qn) + row * 128;
  u32 u = *(const u32*)&p[lane * 2];
  float x0 = b2f((u16)(u & 0xffff)), x1 = b2f((u16)(u >> 16));
  float ss = x0 * x0 + x1 * x1;
#pragma unroll
  for (int o = 32; o > 0; o >>= 1) ss += __shfl_xor(ss, o, 64);
  float sc = 1.f / fmaxf(sqrtf(ss), 1e-12f);
  if (blockIdx.y == 0) sc *= 0.08838834764831845f;  // dh^-0.5
  u32 outv = (u32)f2b(x0 * sc) | ((u32)f2b(x1 * sc) << 16);
  *(u32*)&p[lane * 2] = outv;
}

// ---------------- per-chunk precompute: Minv (Neumann), W2,U,G,KT ----------------
// ST=72: row stride 36 dwords (== 4 mod 32) puts ds_read_b128 fragment reads at
// the bank floor (8 lanes per 4-bank group). ST=80 (== 8 mod 32) was 2x floor.
constexpr int ST = 72;
// 4 LDS buffers (Br, Bc, M0, M1): T = B^2 staged through registers and written
// IN PLACE into Br/Bc -> LDS 61952 -> 37120 B -> 4 blocks/CU (was 2).
__global__ __launch_bounds__(256, 4) void k_pre(
    const float* __restrict__ beta_g,
    const u16* __restrict__ qn, const u16* __restrict__ kn, const u16* __restrict__ vn,
    u16* __restrict__ W2g, u16* __restrict__ Ug, u16* __restrict__ Gg, u16* __restrict__ KTg) {
  __shared__ float beta_s[64];
  __shared__ u16 mats[4 * 64 * ST];
  int gid = blockIdx.x;
  int c = gid & 31, h = (gid >> 5) & 15, b = gid >> 9;
  int tid = threadIdx.x;
  int l0 = c * 64;

  if (tid < 64) beta_s[tid] = beta_g[(size_t)(b * Hn + h) * Ln + l0 + tid];
  __syncthreads();

  int wave = tid >> 6, lane = tid & 63, quad = lane >> 4, l15 = lane & 15;
  u16 *Br = mats, *Bc = mats + 64 * ST, *M0 = mats + 2 * 64 * ST, *M1 = mats + 3 * 64 * ST;

  // P1: A_full = K K^T (MFMA), G = tril(Q K^T); build B=-strict_tril(diag(beta)A), M=I+B
  {
    const u16* krowB = kn + (size_t)(b * Ln + l0 + wave * 16 + l15) * Dn + h * 128;
    short8 bfr[4];
#pragma unroll
    for (int s = 0; s < 4; s++) bfr[s] = *(const short8*)&krowB[quad * 8 + 32 * s];
#pragma unroll
    for (int mt = 0; mt < 4; ++mt) {
      const u16* arow_k = kn + (size_t)(b * Ln + l0 + mt * 16 + l15) * Dn + h * 128;
      const u16* arow_q = qn + (size_t)(b * Ln + l0 + mt * 16 + l15) * Dn + h * 128;
      f32x4 accA = {0.f, 0.f, 0.f, 0.f}, accG = {0.f, 0.f, 0.f, 0.f};
#pragma unroll
      for (int s = 0; s < 4; s++) {
        short8 ak = *(const short8*)&arow_k[quad * 8 + 32 * s];
        short8 aq = *(const short8*)&arow_q[quad * 8 + 32 * s];
        accA = mfma16(ak, bfr[s], accA);
        accG = mfma16(aq, bfr[s], accG);
      }
      int t = wave * 16 + l15;
#pragma unroll
      for (int r = 0; r < 4; r++) {
        int i = mt * 16 + quad * 4 + r;
        u16 nb = f2b((t < i) ? -beta_s[i] * accA[r] : 0.f);
        Br[i * ST + t] = nb;
        Bc[t * ST + i] = nb;
        M0[i * ST + t] = (t == i) ? f2b(1.f) : nb;
        Gg[(size_t)gid * 4096 + (size_t)i * 64 + t] = f2b((t <= i) ? accG[r] : 0.f);
      }
    }
  }
  __syncthreads();

  // P2: Minv = (I+B)(I+B^2)(I+B^4)(I+B^8)(I+B^16)(I+B^32)
  u16 *Mc = M0, *Mn = M1;
#pragma unroll
  for (int it = 0; it < 5; ++it) {
    const int tT = (it < 3) ? 0 : ((it == 3) ? 1 : 2);
    const int tI = (it < 4) ? 0 : 1;
    short8 bb[2];
#pragma unroll
    for (int s = 0; s < 2; s++) bb[s] = *(const short8*)&Bc[(wave * 16 + l15) * ST + quad * 8 + 32 * s];
    f32x4 accT[4];
#pragma unroll
    for (int mt = 0; mt < 4; mt++) {
      accT[mt] = (f32x4){0.f, 0.f, 0.f, 0.f};
      if (mt - wave >= tT) {
#pragma unroll
        for (int s = 0; s < 2; s++) {
          short8 af = *(const short8*)&Br[(mt * 16 + l15) * ST + quad * 8 + 32 * s];
          accT[mt] = mfma16(af, bb[s], accT[mt]);
        }
      }
    }
    __syncthreads();  // all lanes done reading Br/Bc -> safe to overwrite
#pragma unroll
    for (int mt = 0; mt < 4; mt++) {
      if (mt - wave >= tI) {
#pragma unroll
        for (int r = 0; r < 4; r++) {
          int i = mt * 16 + quad * 4 + r, t = wave * 16 + l15;
          u16 v = f2b(accT[mt][r]);
          Br[i * ST + t] = v;
          Bc[t * ST + i] = v;
        }
      }
    }
    __syncthreads();  // T visible
    short8 tb[2];
#pragma unroll
    for (int s = 0; s < 2; s++) tb[s] = *(const short8*)&Bc[(wave * 16 + l15) * ST + quad * 8 + 32 * s];
#pragma unroll
    for (int mt = 0; mt < 4; mt++) {
      if (mt - wave >= tT) {
        f32x4 a;
#pragma unroll
        for (int r = 0; r < 4; r++) a[r] = b2f(Mc[(mt * 16 + quad * 4 + r) * ST + wave * 16 + l15]);
#pragma unroll
        for (int s = 0; s < 2; s++) {
          short8 af = *(const short8*)&Mc[(mt * 16 + l15) * ST + quad * 8 + 32 * s];
          a = mfma16(af, tb[s], a);
        }
#pragma unroll
        for (int r = 0; r < 4; r++) Mn[(mt * 16 + quad * 4 + r) * ST + wave * 16 + l15] = f2b(a[r]);
      } else {
#pragma unroll
        for (int r = 0; r < 4; r++)
          Mn[(mt * 16 + quad * 4 + r) * ST + wave * 16 + l15] =
              Mc[(mt * 16 + quad * 4 + r) * ST + wave * 16 + l15];
      }
    }
    u16* tmp = Mc; Mc = Mn; Mn = tmp;
  }
  __syncthreads();  // drain last M-update before XT reuses Br/Bc

  // P3: W2 = Minv (beta.K), U = Minv (beta.V); also KT (unscaled) to global
  u16* XT = mats;  // scratch slots 0-1 (Br,Bc); Mc lives in slot 3 after 5 swaps
  for (int pass = 0; pass < 2; ++pass) {
    const u16* src = pass ? vn : kn;
    for (int idx = tid; idx < 64 * 128; idx += 256) {
      int t = idx >> 7, dk = idx & 127;
      float v = b2f(src[(size_t)(b * Ln + l0 + t) * Dn + h * 128 + dk]);
      XT[dk * ST + t] = f2b(v * beta_s[t]);
      if (pass == 0) KTg[(size_t)gid * 8192 + (size_t)dk * 64 + t] = f2b(v);
    }
    __syncthreads();
    u16* dst = pass ? Ug : W2g;
#pragma unroll
    for (int half = 0; half < 2; ++half) {
      int nt = wave + half * 4;
      short8 bx[2];
#pragma unroll
      for (int s = 0; s < 2; s++) bx[s] = *(const short8*)&XT[(nt * 16 + l15) * ST + quad * 8 + 32 * s];
#pragma unroll
      for (int mt = 0; mt < 4; mt++) {
        f32x4 a = {0.f, 0.f, 0.f, 0.f};
#pragma unroll
        for (int s = 0; s < 2; s++) {
          short8 af = *(const short8*)&Mc[(mt * 16 + l15) * ST + quad * 8 + 32 * s];
          a = mfma16(af, bx[s], a);
        }
#pragma unroll
        for (int r = 0; r < 4; r++)
          dst[(size_t)gid * 8192 + (size_t)(mt * 16 + quad * 4 + r) * 128 + nt * 16 + l15] = f2b(a[r]);
      }
    }
    __syncthreads();
  }
}

// ---------------- sequential chunk scan (per b,h and 16-wide v-slice) ----------------
struct Frg { short8 w2[4], qf[4], gf[2], k0[2], k1[2]; float u[4]; };

__global__ __launch_bounds__(256) void k_scan(
    const u16* __restrict__ qn, const u16* __restrict__ W2g, const u16* __restrict__ Ug,
    const u16* __restrict__ Gg, const u16* __restrict__ KTg, u16* __restrict__ Og) {
  constexpr int SST = 136, DST = 104;
  __shared__ u16 Sb[16 * SST];  // S^T slice, bf16 shadow: [v][dk]
  __shared__ u16 Db[16 * DST];  // Delta^T slice: [v][t]
  int bh = blockIdx.x, sl = blockIdx.y;
  int b = bh >> 4, h = bh & 15, c0 = sl * 16;
  int tid = threadIdx.x, wave = tid >> 6, lane = tid & 63, quad = lane >> 4, l15 = lane & 15;
  for (int i = tid; i < 16 * SST; i += 256) Sb[i] = 0;
  f32x4 accS0 = {0.f, 0.f, 0.f, 0.f}, accS1 = {0.f, 0.f, 0.f, 0.f};  // fp32 master state
  __syncthreads();

  auto load_frags = [&](Frg& F, int ci) {
    size_t ck = (size_t)bh * NCK + ci;
    const u16* w2row = W2g + ck * 8192 + (size_t)(wave * 16 + l15) * 128;
    const u16* qrow = qn + (size_t)(b * Ln + ci * 64 + wave * 16 + l15) * Dn + h * 128;
#pragma unroll
    for (int s = 0; s < 4; s++) {
      F.w2[s] = *(const short8*)&w2row[quad * 8 + 32 * s];
      F.qf[s] = *(const short8*)&qrow[quad * 8 + 32 * s];
    }
    const u16* grow = Gg + ck * 4096 + (size_t)(wave * 16 + l15) * 64;
    const u16* kt0 = KTg + ck * 8192 + (size_t)(wave * 16 + l15) * 64;
    const u16* kt1 = KTg + ck * 8192 + (size_t)((wave + 4) * 16 + l15) * 64;
#pragma unroll
    for (int s = 0; s < 2; s++) {
      F.gf[s] = *(const short8*)&grow[quad * 8 + 32 * s];
      F.k0[s] = *(const short8*)&kt0[quad * 8 + 32 * s];
      F.k1[s] = *(const short8*)&kt1[quad * 8 + 32 * s];
    }
    const u16* urow = Ug + ck * 8192 + (size_t)(wave * 16 + quad * 4) * 128 + c0 + l15;
#pragma unroll
    for (int r = 0; r < 4; r++) F.u[r] = b2f(urow[(size_t)r * 128]);
  };

  auto compute = [&](const Frg& F, int ci) {
    f32x4 accT = {0.f, 0.f, 0.f, 0.f}, accO = {0.f, 0.f, 0.f, 0.f};
#pragma unroll
    for (int s = 0; s < 4; s++) {
      short8 sf = *(const short8*)&Sb[l15 * SST + quad * 8 + 32 * s];
      accT = mfma16(F.w2[s], sf, accT);   // W2 @ S0
      accO = mfma16(F.qf[s], sf, accO);   // Q @ S0
    }
#pragma unroll
    for (int r = 0; r < 4; r++) {
      float d = F.u[r] - accT[r];         // Delta = U - W2@S0
      Db[l15 * DST + wave * 16 + quad * 4 + r] = f2b(d);
    }
    __syncthreads();
#pragma unroll
    for (int s = 0; s < 2; s++) {
      short8 df = *(const short8*)&Db[l15 * DST + quad * 8 + 32 * s];
      accO = mfma16(F.gf[s], df, accO);   // O += tril(QK^T) @ Delta
      accS0 = mfma16(F.k0[s], df, accS0); // S += K^T @ Delta
      accS1 = mfma16(F.k1[s], df, accS1);
    }
    u16* orow = Og + (size_t)(b * Ln + ci * 64 + wave * 16 + quad * 4) * Dn + h * 128 + c0 + l15;
#pragma unroll
    for (int r = 0; r < 4; r++) orow[(size_t)r * Dn] = f2b(accO[r]);
#pragma unroll
    for (int r = 0; r < 4; r++) {
      Sb[l15 * SST + wave * 16 + quad * 4 + r] = f2b(accS0[r]);
      Sb[l15 * SST + (wave + 4) * 16 + quad * 4 + r] = f2b(accS1[r]);
    }
    __syncthreads();
  };

  Frg FA, FB;
  load_frags(FA, 0);
  for (int ci = 0; ci < NCK; ci += 2) {
    load_frags(FB, ci + 1);
    compute(FA, ci);
    if (ci + 2 < NCK) load_frags(FA, ci + 2);
    compute(FB, ci + 1);
  }
}

// ---------------- RMSNorm over head dim (fp32 weight) ----------------
__global__ void k_rms(const u16* __restrict__ Og, const float* __restrict__ w, u16* __restrict__ out) {
  int tid = threadIdx.x, wave = tid >> 6, lane = tid & 63;
  size_t row = (size_t)blockIdx.x * 4 + wave;
  const u16* p = Og + row * 128;
  u32 u = *(const u32*)&p[lane * 2];
  float x0 = b2f((u16)(u & 0xffff)), x1 = b2f((u16)(u >> 16));
  float ss = x0 * x0 + x1 * x1;
#pragma unroll
  for (int o = 32; o > 0; o >>= 1) ss += __shfl_xor(ss, o, 64);
  float sc = rsqrtf(ss * (1.f / 128.f) + 1e-5f);
  float w0 = w[lane * 2], w1 = w[lane * 2 + 1];
  u32 o2 = (u32)f2b(x0 * sc * w0) | ((u32)f2b(x1 * sc * w1) << 16);
  *(u32*)&out[row * 128 + lane * 2] = o2;
}

// ---------------- host ----------------
extern "C" void kernel_launch(void* const* d_in, const int* in_sizes, int n_in,
                              void* d_out, int out_size, void* d_ws, size_t ws_size,
                              hipStream_t stream) {
  (void)in_sizes; (void)n_in; (void)out_size; (void)ws_size;
  const float* hs_f = (const float*)d_in[0];
  const float* Wq = (const float*)d_in[1];
  const float* Wk = (const float*)d_in[2];
  const float* Wv = (const float*)d_in[3];
  const float* Wb = (const float*)d_in[4];
  const float* onw = (const float*)d_in[5];
  const float* Wo = (const float*)d_in[6];

  char* ws = (char*)d_ws;
  size_t off = 0;
  auto alloc = [&](size_t bytes) -> void* {
    void* p = ws + off;
    off += (bytes + 255) & ~(size_t)255;
    return p;
  };
  const size_t WB = (size_t)2048 * 2048 * 2;
  const size_t XB = (size_t)4096 * 2048 * 2;
  u16* WqT = (u16*)alloc(WB);   // WqT|WkT|WvT contiguous => fused Bt [6144][2048]
  u16* WkT = (u16*)alloc(WB);
  u16* WvT = (u16*)alloc(WB);
  u16* WoT = (u16*)alloc(WB);
  u16* WbT = (u16*)alloc((size_t)16 * 2048 * 2);
  u16* hsb = (u16*)alloc(XB);
  u16* qn  = (u16*)alloc(XB);   // qn|kn|vn contiguous => fused C
  u16* kn  = (u16*)alloc(XB);
  u16* vn  = (u16*)alloc(XB);   // reused as O after precompute
  u16* W2g = (u16*)alloc((size_t)NCHUNKS * 8192 * 2);
  u16* Ug  = (u16*)alloc((size_t)NCHUNKS * 8192 * 2);
  u16* Gg  = (u16*)alloc((size_t)NCHUNKS * 4096 * 2);
  u16* KTg = (u16*)alloc((size_t)NCHUNKS * 8192 * 2);
  float* beta_g = (float*)alloc((size_t)Bn * Hn * Ln * 4);
  u16* Og = vn;       // v dead after precompute
  u16* onorm = qn;    // q dead after scan

  // 0) downcast hidden_states
  hipLaunchKernelGGL(k_cvt, dim3(Mrows * Dn / 8 / 256), dim3(256), 0, stream, hs_f, hsb, Mrows * Dn / 8);

  // 1) transposes + downcast
  TransArgs ta;
  ta.src[0] = Wq; ta.dst[0] = WqT; ta.rows[0] = 2048; ta.cols[0] = 2048;
  ta.src[1] = Wk; ta.dst[1] = WkT; ta.rows[1] = 2048; ta.cols[1] = 2048;
  ta.src[2] = Wv; ta.dst[2] = WvT; ta.rows[2] = 2048; ta.cols[2] = 2048;
  ta.src[3] = Wo; ta.dst[3] = WoT; ta.rows[3] = 2048; ta.cols[3] = 2048;
  ta.src[4] = Wb; ta.dst[4] = WbT; ta.rows[4] = 2048; ta.cols[4] = 16;
  hipLaunchKernelGGL(k_trans, dim3(64, 64, 5), dim3(32, 8), 0, stream, ta);

  // 1b) beta for all heads (reads hs once)
  hipLaunchKernelGGL(k_beta, dim3(Mrows / 64), dim3(256), 0, stream, hsb, WbT, beta_g);

  // 2) fused q/k/v projection: one 4096x6144x2048 GEMM on the 256^2 pipeline
  {
    Gemm2Args g2;
    g2.A = hsb; g2.Bt = WqT; g2.C = qn; g2.K = 2048;
    hipLaunchKernelGGL(k_gemm2, dim3(384), dim3(512), 0, stream, g2);
  }

  // 3) l2 normalize q (with dh^-0.5) and k
  hipLaunchKernelGGL(k_l2, dim3(16384, 2), dim3(256), 0, stream, qn, kn);

  // 4) chunk precompute
  hipLaunchKernelGGL(k_pre, dim3(NCHUNKS), dim3(256), 0, stream,
                     beta_g, qn, kn, vn, W2g, Ug, Gg, KTg);

  // 5) sequential scan
  hipLaunchKernelGGL(k_scan, dim3(32, 8), dim3(256), 0, stream,
                     qn, W2g, Ug, Gg, KTg, Og);

  // 6) RMSNorm
  hipLaunchKernelGGL(k_rms, dim3(16384), dim3(256), 0, stream, Og, onw, onorm);

  // 7) output projection (fp32 out -> d_out)
  GemmArgs go;
  go.A = onorm; go.Bt = WoT; go.C = d_out; go.epi = 0;
  go.f32out = 1; go.M = Mrows; go.N = 2048; go.K = 2048;
  hipLaunchKernelGGL(k_gemm, dim3(16, 32), dim3(256), 0, stream, go);
}

// Round 3
// 497.761 us; speedup vs baseline: 1.0992x; 1.0247x over previous
//
#include <hip/hip_runtime.h>
#include <hip/hip_bf16.h>
#include <cstdint>

#define DEV static __device__ __forceinline__

typedef unsigned short u16;
typedef unsigned int u32;
typedef __attribute__((ext_vector_type(8))) short short8;
typedef __attribute__((ext_vector_type(4))) float f32x4;

constexpr int Bn = 2, Ln = 2048, Dn = 2048, Hn = 16;
constexpr int Mrows = Bn * Ln;          // 4096
constexpr int CHK = 64, NCK = Ln / CHK; // chunk=64, 32 chunks/seq
constexpr int NCHUNKS = Bn * Hn * NCK;  // 1024

DEV float b2f(u16 s) { union { float f; u32 u; } x; x.u = ((u32)s) << 16; return x.f; }
DEV u16 f2b(float f) {
  union { float f; u32 u; } x; x.f = f; u32 u = x.u;
  return (u16)((u + 0x7fffu + ((u >> 16) & 1u)) >> 16);  // RNE
}

DEV void cp16(const void* g, void* l) {
  __builtin_amdgcn_global_load_lds(
      (const __attribute__((address_space(1))) u32*)(unsigned long long)(g),
      (__attribute__((address_space(3))) u32*)(unsigned long long)(l), 16, 0, 0);
}

DEV f32x4 mfma16(short8 a, short8 b, f32x4 c) {
  return __builtin_amdgcn_mfma_f32_16x16x32_bf16(a, b, c, 0, 0, 0);
}

// ---------------- fp32 -> bf16 elementwise convert ----------------
__global__ void k_cvt(const float* __restrict__ src, u16* __restrict__ dst, int n8) {
  int i = blockIdx.x * blockDim.x + threadIdx.x;
  if (i >= n8) return;
  const float4* s4 = (const float4*)(src + (size_t)i * 8);
  float4 a = s4[0], b = s4[1];
  u16 o[8] = {f2b(a.x), f2b(a.y), f2b(a.z), f2b(a.w), f2b(b.x), f2b(b.y), f2b(b.z), f2b(b.w)};
  *(short8*)(dst + (size_t)i * 8) = *(short8*)o;
}

// ---------------- transpose + downcast (fp32 weights -> bf16 B^T form) ----------------
struct TransArgs {
  const float* src[5]; u16* dst[5]; int rows[5]; int cols[5];
};
__global__ void k_trans(TransArgs t) {
  __shared__ u16 tile[32][33];
  int z = blockIdx.z;
  const float* src = t.src[z]; u16* dst = t.dst[z];
  int rows = t.rows[z], cols = t.cols[z];
  int r0 = blockIdx.y * 32, c0 = blockIdx.x * 32;
  if (r0 >= rows || c0 >= cols) return;
  int tx = threadIdx.x, ty = threadIdx.y;
  for (int i = ty; i < 32; i += 8) {
    int r = r0 + i, c = c0 + tx;
    if (r < rows && c < cols) tile[i][tx] = f2b(src[(size_t)r * cols + c]);
  }
  __syncthreads();
  for (int i = ty; i < 32; i += 8) {
    int r = c0 + i, c = r0 + tx;
    if (r < cols && c < rows) dst[(size_t)r * rows + c] = tile[tx][i];
  }
}

// ---------------- beta = sigmoid(hs @ Wb) for all heads, MFMA GEMV ----------------
__global__ __launch_bounds__(256) void k_beta(const u16* __restrict__ hs,
                                              const u16* __restrict__ WbT,
                                              float* __restrict__ beta_g) {
  int tid = threadIdx.x, wave = tid >> 6, lane = tid & 63, quad = lane >> 4, l15 = lane & 15;
  int tok0 = blockIdx.x * 64 + wave * 16;
  const u16* arow = hs + (size_t)(tok0 + l15) * Dn;   // A[m=l15][k]
  const u16* brow = WbT + (size_t)l15 * Dn;           // B[n=head=l15][k]
  f32x4 acc = {0.f, 0.f, 0.f, 0.f};
  for (int k = 0; k < Dn; k += 32) {
    short8 af = *(const short8*)&arow[k + quad * 8];
    short8 bf = *(const short8*)&brow[k + quad * 8];
    acc = mfma16(af, bf, acc);
  }
  int b = (blockIdx.x * 64) >> 11;
  int l = (blockIdx.x * 64 + wave * 16) & 2047;
#pragma unroll
  for (int r = 0; r < 4; r++) {
    beta_g[(size_t)(b * Hn + l15) * Ln + l + quad * 4 + r] = 1.f / (1.f + __expf(-acc[r]));
  }
}

// ---------------- 128x128-tile MFMA GEMM, C = act(A @ Bt^T) ----------------
struct GemmArgs {
  const u16* A; const u16* Bt; void* C; int epi;  // epi: 0 none, 1 silu
  int f32out;
  int M, N, K;
};
__global__ __launch_bounds__(256) void k_gemm(GemmArgs g) {
  __shared__ u16 As[128 * 64];
  __shared__ u16 Bs[128 * 64];
  const u16* A = g.A; const u16* Bt = g.Bt;
  int epi = g.epi;
  int K = g.K, N = g.N;
  int tid = threadIdx.x, wave = tid >> 6, lane = tid & 63;
  int quad = lane >> 4, l15 = lane & 15;
  int m0 = blockIdx.y * 128, n0 = blockIdx.x * 128;
  int wm = (wave >> 1) * 64, wn = (wave & 1) * 64;
  f32x4 acc[4][4];
#pragma unroll
  for (int i = 0; i < 4; i++)
#pragma unroll
    for (int j = 0; j < 4; j++) acc[i][j] = (f32x4){0.f, 0.f, 0.f, 0.f};
  const u16* Ag = A + (size_t)(m0 + wave * 32 + (lane >> 3)) * K + (lane & 7) * 8;
  const u16* Bg = Bt + (size_t)(n0 + wave * 32 + (lane >> 3)) * K + (lane & 7) * 8;
  u16* Al = &As[wave * 32 * 64];
  u16* Bl = &Bs[wave * 32 * 64];
  for (int k0 = 0; k0 < K; k0 += 64) {
#pragma unroll
    for (int t = 0; t < 4; t++) {
      cp16(Ag + k0 + t * 8 * K, Al + t * 8 * 64);
      cp16(Bg + k0 + t * 8 * K, Bl + t * 8 * 64);
    }
    __syncthreads();
#pragma unroll
    for (int kk = 0; kk < 64; kk += 32) {
      short8 af[4], bf[4];
#pragma unroll
      for (int i = 0; i < 4; i++) af[i] = *(const short8*)&As[(wm + i * 16 + l15) * 64 + kk + quad * 8];
#pragma unroll
      for (int i = 0; i < 4; i++) bf[i] = *(const short8*)&Bs[(wn + i * 16 + l15) * 64 + kk + quad * 8];
#pragma unroll
      for (int i = 0; i < 4; i++)
#pragma unroll
        for (int j = 0; j < 4; j++) acc[i][j] = mfma16(af[i], bf[j], acc[i][j]);
    }
    __syncthreads();
  }
#pragma unroll
  for (int i = 0; i < 4; i++)
#pragma unroll
    for (int j = 0; j < 4; j++) {
      int row = m0 + wm + i * 16 + quad * 4;
      int col = n0 + wn + j * 16 + l15;
#pragma unroll
      for (int r = 0; r < 4; r++) {
        float v = acc[i][j][r];
        if (epi == 1) v = v / (1.f + __expf(-v));  // silu
        if (g.f32out) ((float*)g.C)[(size_t)(row + r) * N + col] = v;
        else ((u16*)g.C)[(size_t)(row + r) * N + col] = f2b(v);
      }
    }
}

// ---------------- fused QKV GEMM: 256x384 tile, 4-phase unit pipeline ----------------
// A [4096][2048], Bt [6144][2048] (WqT|WkT|WvT), C base = qn (qn|kn|vn contiguous).
// Stage unit = 32 K-cols: A-unit 256x32 (16KB, 2 loads/thr), B-unit 384x32 (24KB, 3).
// Ring-3 slots per operand; stage->consume distance 3-4 phases; vmcnt(5) per phase
// (2 units in flight), never 0 in main loop. 64B unit rows => ds_read_b128 frag
// reads are contiguous-1KB => bank-conflict-free, no swizzle needed on either side.
struct Gemm2Args { const u16* A; const u16* Bt; u16* C; int K; };

__global__ __launch_bounds__(512, 2) void k_gemm2(Gemm2Args g) {
  // A slots: 3 x 16384B at 0; B slots: 3 x 24576B at 49152. Total 122880B.
  __shared__ u16 ldsbuf[61440];
  const char* LB = (const char*)ldsbuf;
  const int K = g.K, NT = K / 64;
  const size_t Kb = (size_t)K * 2;
  int tid = threadIdx.x, wave = tid >> 6, lane = tid & 63;
  int quad = lane >> 4, l15 = lane & 15;
  int wm = wave >> 2, wn = wave & 3;  // 2M x 4N wave grid; per-wave C = 128x96

  // XCD-aware swizzle (256 % 8 == 0): each XCD gets a contiguous 32-block chunk
  int bid = blockIdx.x;
  int wg = (bid & 7) * 32 + (bid >> 3);
  int by = wg >> 4, bx = wg & 15;   // 16 x 16 tiles
  int m0 = by * 256, n0f = bx * 384;

  // staging: thread covers row r0 (+128/s), col-bytes cby within the 64B unit row
  int r0 = tid >> 2;
  int cby = (tid & 3) * 16;
  const char* gA = (const char*)g.A + (size_t)(m0 + r0) * Kb + cby;
  const char* gB = (const char*)g.Bt + (size_t)(n0f + r0) * Kb + cby;

  auto stageA = [&](int slot, int t, int kh) {
    const char* src = gA + (size_t)t * 128 + kh * 64;
    u16* dst = &ldsbuf[slot * 8192 + tid * 8];
    cp16(src, dst);
    cp16(src + (size_t)128 * Kb, dst + 4096);
  };
  auto stageB = [&](int slot, int t, int kh) {
    const char* src = gB + (size_t)t * 128 + kh * 64;
    u16* dst = &ldsbuf[24576 + slot * 12288 + tid * 8];
    cp16(src, dst);
    cp16(src + (size_t)128 * Kb, dst + 4096);
    cp16(src + (size_t)256 * Kb, dst + 8192);
  };

  f32x4 acc0[4][6], acc1[4][6];
#pragma unroll
  for (int i = 0; i < 4; i++)
#pragma unroll
    for (int j = 0; j < 6; j++) {
      acc0[i][j] = (f32x4){0.f, 0.f, 0.f, 0.f};
      acc1[i][j] = (f32x4){0.f, 0.f, 0.f, 0.f};
    }

  // frag byte offsets within a unit (row*64 + quad*16); contiguous 1KB per frag set
  int rA = (wm * 128 + l15) * 64 + quad * 16;  // + mq*4096 + i*1024
  int rB = (wn * 96 + l15) * 64 + quad * 16;   // + j*1024

  // prologue: stage tile 0 (units into slots 0,0,1,1)
  stageA(0, 0, 0);
  stageB(0, 0, 0);
  stageA(1, 0, 1);
  stageB(1, 0, 1);

  short8 bf[6];
  int u0 = 0;
  for (int t = 0; t < NT; ++t) {
    int u1 = u0 + 1; if (u1 == 3) u1 = 0;
    int u2 = u1 + 1; if (u2 == 3) u2 = 0;
    bool pf = (t + 1 < NT);
    const char* aK0 = LB + u0 * 16384;
    const char* aK1 = LB + u1 * 16384;
    const char* bK0 = LB + 49152 + u0 * 24576;
    const char* bK1 = LB + 49152 + u1 * 24576;

    // ---- phase 0: (mq=0, kh=0); stage A(t+1,0) -> u2 ----
    asm volatile("s_waitcnt vmcnt(5)" ::: "memory");
    __builtin_amdgcn_s_barrier();
    __builtin_amdgcn_sched_barrier(0);
    if (pf) stageA(u2, t + 1, 0);
    {
      short8 av[4];
#pragma unroll
      for (int i = 0; i < 4; i++) av[i] = *(const short8*)(aK0 + rA + i * 1024);
#pragma unroll
      for (int j = 0; j < 6; j++) bf[j] = *(const short8*)(bK0 + rB + j * 1024);
      __builtin_amdgcn_s_setprio(1);
#pragma unroll
      for (int i = 0; i < 4; i++)
#pragma unroll
        for (int j = 0; j < 6; j++) acc0[i][j] = mfma16(av[i], bf[j], acc0[i][j]);
      __builtin_amdgcn_s_setprio(0);
    }

    // ---- phase 1: (mq=1, kh=0); stage B(t+1,0) -> u2 ----
    asm volatile("s_waitcnt vmcnt(5)" ::: "memory");
    __builtin_amdgcn_s_barrier();
    __builtin_amdgcn_sched_barrier(0);
    if (pf) stageB(u2, t + 1, 0);
    {
      short8 av[4];
#pragma unroll
      for (int i = 0; i < 4; i++) av[i] = *(const short8*)(aK0 + rA + 4096 + i * 1024);
      __builtin_amdgcn_s_setprio(1);
#pragma unroll
      for (int i = 0; i < 4; i++)
#pragma unroll
        for (int j = 0; j < 6; j++) acc1[i][j] = mfma16(av[i], bf[j], acc1[i][j]);
      __builtin_amdgcn_s_setprio(0);
    }

    // ---- phase 2: (mq=0, kh=1); stage A(t+1,1) -> u0 ----
    if (t == NT - 1) asm volatile("s_waitcnt vmcnt(0)" ::: "memory");
    else asm volatile("s_waitcnt vmcnt(5)" ::: "memory");
    __builtin_amdgcn_s_barrier();
    __builtin_amdgcn_sched_barrier(0);
    if (pf) stageA(u0, t + 1, 1);
    {
      short8 av[4];
#pragma unroll
      for (int i = 0; i < 4; i++) av[i] = *(const short8*)(aK1 + rA + i * 1024);
#pragma unroll
      for (int j = 0; j < 6; j++) bf[j] = *(const short8*)(bK1 + rB + j * 1024);
      __builtin_amdgcn_s_setprio(1);
#pragma unroll
      for (int i = 0; i < 4; i++)
#pragma unroll
        for (int j = 0; j < 6; j++) acc0[i][j] = mfma16(av[i], bf[j], acc0[i][j]);
      __builtin_amdgcn_s_setprio(0);
    }

    // ---- phase 3: (mq=1, kh=1); stage B(t+1,1) -> u0 ----
    asm volatile("s_waitcnt vmcnt(5)" ::: "memory");
    __builtin_amdgcn_s_barrier();
    __builtin_amdgcn_sched_barrier(0);
    if (pf) stageB(u0, t + 1, 1);
    {
      short8 av[4];
#pragma unroll
      for (int i = 0; i < 4; i++) av[i] = *(const short8*)(aK1 + rA + 4096 + i * 1024);
      __builtin_amdgcn_s_setprio(1);
#pragma unroll
      for (int i = 0; i < 4; i++)
#pragma unroll
        for (int j = 0; j < 6; j++) acc1[i][j] = mfma16(av[i], bf[j], acc1[i][j]);
      __builtin_amdgcn_s_setprio(0);
    }

    u0 = u2;
  }

  // epilogue: per-fragment z selection across the q/k/v boundary
#pragma unroll
  for (int mq = 0; mq < 2; mq++) {
#pragma unroll
    for (int i = 0; i < 4; i++)
#pragma unroll
      for (int j = 0; j < 6; j++) {
        f32x4 a = mq ? acc1[i][j] : acc0[i][j];
        int row = m0 + wm * 128 + mq * 64 + i * 16 + quad * 4;
        int colg = n0f + wn * 96 + j * 16;
        int z = colg >> 11;
        u16* Cz = g.C + (size_t)z * ((size_t)Mrows * 2048);
        int col = (colg & 2047) + l15;
#pragma unroll
        for (int r = 0; r < 4; r++) {
          float v = a[r];
          if (z == 2) v = v / (1.f + __expf(-v));  // silu (v-projection)
          Cz[(size_t)(row + r) * 2048 + col] = f2b(v);
        }
      }
  }
}

// ---------------- l2-normalize q,k rows of 128 (in place, bf16) ----------------
__global__ void k_l2(u16* qn, u16* kn) {
  int tid = threadIdx.x, wave = tid >> 6, lane = tid & 63;
  size_t row = (size_t)blockIdx.x * 4 + wave;  // (b*L+l)*16+h
  u16* p = (blockIdx.y ? kn : qn) + row * 128;
  u32 u = *(const u32*)&p[lane * 2];
  float x0 = b2f((u16)(u & 0xffff)), x1 = b2f((u16)(u >> 16));
  float ss = x0 * x0 + x1 * x1;
#pragma unroll
  for (int o = 32; o > 0; o >>= 1) ss += __shfl_xor(ss, o, 64);
  float sc = 1.f / fmaxf(sqrtf(ss), 1e-12f);
  if (blockIdx.y == 0) sc *= 0.08838834764831845f;  // dh^-0.5
  u32 outv = (u32)f2b(x0 * sc) | ((u32)f2b(x1 * sc) << 16);
  *(u32*)&p[lane * 2] = outv;
}

// ---------------- per-chunk precompute: Minv (Neumann), W2,U,G,KT ----------------
// ST=72: row stride 36 dwords (== 4 mod 32) puts ds_read_b128 fragment reads at
// the bank floor (8 lanes per 4-bank group). ST=80 (== 8 mod 32) was 2x floor.
constexpr int ST = 72;
// 4 LDS buffers (Br, Bc, M0, M1): T = B^2 staged through registers and written
// IN PLACE into Br/Bc -> LDS 61952 -> 37120 B -> 4 blocks/CU (was 2).
__global__ __launch_bounds__(256, 4) void k_pre(
    const float* __restrict__ beta_g,
    const u16* __restrict__ qn, const u16* __restrict__ kn, const u16* __restrict__ vn,
    u16* __restrict__ W2g, u16* __restrict__ Ug, u16* __restrict__ Gg, u16* __restrict__ KTg) {
  __shared__ float beta_s[64];
  __shared__ u16 mats[4 * 64 * ST];
  int gid = blockIdx.x;
  int c = gid & 31, h = (gid >> 5) & 15, b = gid >> 9;
  int tid = threadIdx.x;
  int l0 = c * 64;

  if (tid < 64) beta_s[tid] = beta_g[(size_t)(b * Hn + h) * Ln + l0 + tid];
  __syncthreads();

  int wave = tid >> 6, lane = tid & 63, quad = lane >> 4, l15 = lane & 15;
  u16 *Br = mats, *Bc = mats + 64 * ST, *M0 = mats + 2 * 64 * ST, *M1 = mats + 3 * 64 * ST;

  // P1: A_full = K K^T (MFMA), G = tril(Q K^T); build B=-strict_tril(diag(beta)A), M=I+B
  {
    const u16* krowB = kn + (size_t)(b * Ln + l0 + wave * 16 + l15) * Dn + h * 128;
    short8 bfr[4];
#pragma unroll
    for (int s = 0; s < 4; s++) bfr[s] = *(const short8*)&krowB[quad * 8 + 32 * s];
#pragma unroll
    for (int mt = 0; mt < 4; ++mt) {
      const u16* arow_k = kn + (size_t)(b * Ln + l0 + mt * 16 + l15) * Dn + h * 128;
      const u16* arow_q = qn + (size_t)(b * Ln + l0 + mt * 16 + l15) * Dn + h * 128;
      f32x4 accA = {0.f, 0.f, 0.f, 0.f}, accG = {0.f, 0.f, 0.f, 0.f};
#pragma unroll
      for (int s = 0; s < 4; s++) {
        short8 ak = *(const short8*)&arow_k[quad * 8 + 32 * s];
        short8 aq = *(const short8*)&arow_q[quad * 8 + 32 * s];
        accA = mfma16(ak, bfr[s], accA);
        accG = mfma16(aq, bfr[s], accG);
      }
      int t = wave * 16 + l15;
#pragma unroll
      for (int r = 0; r < 4; r++) {
        int i = mt * 16 + quad * 4 + r;
        u16 nb = f2b((t < i) ? -beta_s[i] * accA[r] : 0.f);
        Br[i * ST + t] = nb;
        Bc[t * ST + i] = nb;
        M0[i * ST + t] = (t == i) ? f2b(1.f) : nb;
        Gg[(size_t)gid * 4096 + (size_t)i * 64 + t] = f2b((t <= i) ? accG[r] : 0.f);
      }
    }
  }
  __syncthreads();

  // P2: Minv = (I+B)(I+B^2)(I+B^4)(I+B^8)(I+B^16)(I+B^32)
  u16 *Mc = M0, *Mn = M1;
#pragma unroll
  for (int it = 0; it < 5; ++it) {
    const int tT = (it < 3) ? 0 : ((it == 3) ? 1 : 2);
    const int tI = (it < 4) ? 0 : 1;
    short8 bb[2];
#pragma unroll
    for (int s = 0; s < 2; s++) bb[s] = *(const short8*)&Bc[(wave * 16 + l15) * ST + quad * 8 + 32 * s];
    f32x4 accT[4];
#pragma unroll
    for (int mt = 0; mt < 4; mt++) {
      accT[mt] = (f32x4){0.f, 0.f, 0.f, 0.f};
      if (mt - wave >= tT) {
#pragma unroll
        for (int s = 0; s < 2; s++) {
          short8 af = *(const short8*)&Br[(mt * 16 + l15) * ST + quad * 8 + 32 * s];
          accT[mt] = mfma16(af, bb[s], accT[mt]);
        }
      }
    }
    __syncthreads();  // all lanes done reading Br/Bc -> safe to overwrite
#pragma unroll
    for (int mt = 0; mt < 4; mt++) {
      if (mt - wave >= tI) {
#pragma unroll
        for (int r = 0; r < 4; r++) {
          int i = mt * 16 + quad * 4 + r, t = wave * 16 + l15;
          u16 v = f2b(accT[mt][r]);
          Br[i * ST + t] = v;
          Bc[t * ST + i] = v;
        }
      }
    }
    __syncthreads();  // T visible
    short8 tb[2];
#pragma unroll
    for (int s = 0; s < 2; s++) tb[s] = *(const short8*)&Bc[(wave * 16 + l15) * ST + quad * 8 + 32 * s];
#pragma unroll
    for (int mt = 0; mt < 4; mt++) {
      if (mt - wave >= tT) {
        f32x4 a;
#pragma unroll
        for (int r = 0; r < 4; r++) a[r] = b2f(Mc[(mt * 16 + quad * 4 + r) * ST + wave * 16 + l15]);
#pragma unroll
        for (int s = 0; s < 2; s++) {
          short8 af = *(const short8*)&Mc[(mt * 16 + l15) * ST + quad * 8 + 32 * s];
          a = mfma16(af, tb[s], a);
        }
#pragma unroll
        for (int r = 0; r < 4; r++) Mn[(mt * 16 + quad * 4 + r) * ST + wave * 16 + l15] = f2b(a[r]);
      } else {
#pragma unroll
        for (int r = 0; r < 4; r++)
          Mn[(mt * 16 + quad * 4 + r) * ST + wave * 16 + l15] =
              Mc[(mt * 16 + quad * 4 + r) * ST + wave * 16 + l15];
      }
    }
    u16* tmp = Mc; Mc = Mn; Mn = tmp;
  }
  __syncthreads();  // drain last M-update before XT reuses Br/Bc

  // P3: W2 = Minv (beta.K), U = Minv (beta.V); also KT (unscaled) to global
  u16* XT = mats;  // scratch slots 0-1 (Br,Bc); Mc lives in slot 3 after 5 swaps
  for (int pass = 0; pass < 2; ++pass) {
    const u16* src = pass ? vn : kn;
    for (int idx = tid; idx < 64 * 128; idx += 256) {
      int t = idx >> 7, dk = idx & 127;
      float v = b2f(src[(size_t)(b * Ln + l0 + t) * Dn + h * 128 + dk]);
      XT[dk * ST + t] = f2b(v * beta_s[t]);
      if (pass == 0) KTg[(size_t)gid * 8192 + (size_t)dk * 64 + t] = f2b(v);
    }
    __syncthreads();
    u16* dst = pass ? Ug : W2g;
#pragma unroll
    for (int half = 0; half < 2; ++half) {
      int nt = wave + half * 4;
      short8 bx[2];
#pragma unroll
      for (int s = 0; s < 2; s++) bx[s] = *(const short8*)&XT[(nt * 16 + l15) * ST + quad * 8 + 32 * s];
#pragma unroll
      for (int mt = 0; mt < 4; mt++) {
        f32x4 a = {0.f, 0.f, 0.f, 0.f};
#pragma unroll
        for (int s = 0; s < 2; s++) {
          short8 af = *(const short8*)&Mc[(mt * 16 + l15) * ST + quad * 8 + 32 * s];
          a = mfma16(af, bx[s], a);
        }
#pragma unroll
        for (int r = 0; r < 4; r++)
          dst[(size_t)gid * 8192 + (size_t)(mt * 16 + quad * 4 + r) * 128 + nt * 16 + l15] = f2b(a[r]);
      }
    }
    __syncthreads();
  }
}

// ---------------- sequential chunk scan (per b,h and 16-wide v-slice) ----------------
struct Frg { short8 w2[4], qf[4], gf[2], k0[2], k1[2]; float u[4]; };

__global__ __launch_bounds__(256) void k_scan(
    const u16* __restrict__ qn, const u16* __restrict__ W2g, const u16* __restrict__ Ug,
    const u16* __restrict__ Gg, const u16* __restrict__ KTg, u16* __restrict__ Og) {
  constexpr int SST = 136, DST = 104;
  __shared__ u16 Sb[16 * SST];  // S^T slice, bf16 shadow: [v][dk]
  __shared__ u16 Db[16 * DST];  // Delta^T slice: [v][t]
  int bh = blockIdx.x, sl = blockIdx.y;
  int b = bh >> 4, h = bh & 15, c0 = sl * 16;
  int tid = threadIdx.x, wave = tid >> 6, lane = tid & 63, quad = lane >> 4, l15 = lane & 15;
  for (int i = tid; i < 16 * SST; i += 256) Sb[i] = 0;
  f32x4 accS0 = {0.f, 0.f, 0.f, 0.f}, accS1 = {0.f, 0.f, 0.f, 0.f};  // fp32 master state
  __syncthreads();

  auto load_frags = [&](Frg& F, int ci) {
    size_t ck = (size_t)bh * NCK + ci;
    const u16* w2row = W2g + ck * 8192 + (size_t)(wave * 16 + l15) * 128;
    const u16* qrow = qn + (size_t)(b * Ln + ci * 64 + wave * 16 + l15) * Dn + h * 128;
#pragma unroll
    for (int s = 0; s < 4; s++) {
      F.w2[s] = *(const short8*)&w2row[quad * 8 + 32 * s];
      F.qf[s] = *(const short8*)&qrow[quad * 8 + 32 * s];
    }
    const u16* grow = Gg + ck * 4096 + (size_t)(wave * 16 + l15) * 64;
    const u16* kt0 = KTg + ck * 8192 + (size_t)(wave * 16 + l15) * 64;
    const u16* kt1 = KTg + ck * 8192 + (size_t)((wave + 4) * 16 + l15) * 64;
#pragma unroll
    for (int s = 0; s < 2; s++) {
      F.gf[s] = *(const short8*)&grow[quad * 8 + 32 * s];
      F.k0[s] = *(const short8*)&kt0[quad * 8 + 32 * s];
      F.k1[s] = *(const short8*)&kt1[quad * 8 + 32 * s];
    }
    const u16* urow = Ug + ck * 8192 + (size_t)(wave * 16 + quad * 4) * 128 + c0 + l15;
#pragma unroll
    for (int r = 0; r < 4; r++) F.u[r] = b2f(urow[(size_t)r * 128]);
  };

  auto compute = [&](const Frg& F, int ci) {
    f32x4 accT = {0.f, 0.f, 0.f, 0.f}, accO = {0.f, 0.f, 0.f, 0.f};
#pragma unroll
    for (int s = 0; s < 4; s++) {
      short8 sf = *(const short8*)&Sb[l15 * SST + quad * 8 + 32 * s];
      accT = mfma16(F.w2[s], sf, accT);   // W2 @ S0
      accO = mfma16(F.qf[s], sf, accO);   // Q @ S0
    }
#pragma unroll
    for (int r = 0; r < 4; r++) {
      float d = F.u[r] - accT[r];         // Delta = U - W2@S0
      Db[l15 * DST + wave * 16 + quad * 4 + r] = f2b(d);
    }
    __syncthreads();
#pragma unroll
    for (int s = 0; s < 2; s++) {
      short8 df = *(const short8*)&Db[l15 * DST + quad * 8 + 32 * s];
      accO = mfma16(F.gf[s], df, accO);   // O += tril(QK^T) @ Delta
      accS0 = mfma16(F.k0[s], df, accS0); // S += K^T @ Delta
      accS1 = mfma16(F.k1[s], df, accS1);
    }
    u16* orow = Og + (size_t)(b * Ln + ci * 64 + wave * 16 + quad * 4) * Dn + h * 128 + c0 + l15;
#pragma unroll
    for (int r = 0; r < 4; r++) orow[(size_t)r * Dn] = f2b(accO[r]);
#pragma unroll
    for (int r = 0; r < 4; r++) {
      Sb[l15 * SST + wave * 16 + quad * 4 + r] = f2b(accS0[r]);
      Sb[l15 * SST + (wave + 4) * 16 + quad * 4 + r] = f2b(accS1[r]);
    }
    __syncthreads();
  };

  Frg FA, FB;
  load_frags(FA, 0);
  for (int ci = 0; ci < NCK; ci += 2) {
    load_frags(FB, ci + 1);
    compute(FA, ci);
    if (ci + 2 < NCK) load_frags(FA, ci + 2);
    compute(FB, ci + 1);
  }
}

// ---------------- RMSNorm over head dim (fp32 weight) ----------------
__global__ void k_rms(const u16* __restrict__ Og, const float* __restrict__ w, u16* __restrict__ out) {
  int tid = threadIdx.x, wave = tid >> 6, lane = tid & 63;
  size_t row = (size_t)blockIdx.x * 4 + wave;
  const u16* p = Og + row * 128;
  u32 u = *(const u32*)&p[lane * 2];
  float x0 = b2f((u16)(u & 0xffff)), x1 = b2f((u16)(u >> 16));
  float ss = x0 * x0 + x1 * x1;
#pragma unroll
  for (int o = 32; o > 0; o >>= 1) ss += __shfl_xor(ss, o, 64);
  float sc = rsqrtf(ss * (1.f / 128.f) + 1e-5f);
  float w0 = w[lane * 2], w1 = w[lane * 2 + 1];
  u32 o2 = (u32)f2b(x0 * sc * w0) | ((u32)f2b(x1 * sc * w1) << 16);
  *(u32*)&out[row * 128 + lane * 2] = o2;
}

// ---------------- host ----------------
extern "C" void kernel_launch(void* const* d_in, const int* in_sizes, int n_in,
                              void* d_out, int out_size, void* d_ws, size_t ws_size,
                              hipStream_t stream) {
  (void)in_sizes; (void)n_in; (void)out_size; (void)ws_size;
  const float* hs_f = (const float*)d_in[0];
  const float* Wq = (const float*)d_in[1];
  const float* Wk = (const float*)d_in[2];
  const float* Wv = (const float*)d_in[3];
  const float* Wb = (const float*)d_in[4];
  const float* onw = (const float*)d_in[5];
  const float* Wo = (const float*)d_in[6];

  char* ws = (char*)d_ws;
  size_t off = 0;
  auto alloc = [&](size_t bytes) -> void* {
    void* p = ws + off;
    off += (bytes + 255) & ~(size_t)255;
    return p;
  };
  const size_t WB = (size_t)2048 * 2048 * 2;
  const size_t XB = (size_t)4096 * 2048 * 2;
  u16* WqT = (u16*)alloc(WB);   // WqT|WkT|WvT contiguous => fused Bt [6144][2048]
  u16* WkT = (u16*)alloc(WB);
  u16* WvT = (u16*)alloc(WB);
  u16* WoT = (u16*)alloc(WB);
  u16* WbT = (u16*)alloc((size_t)16 * 2048 * 2);
  u16* hsb = (u16*)alloc(XB);
  u16* qn  = (u16*)alloc(XB);   // qn|kn|vn contiguous => fused C
  u16* kn  = (u16*)alloc(XB);
  u16* vn  = (u16*)alloc(XB);   // reused as O after precompute
  u16* W2g = (u16*)alloc((size_t)NCHUNKS * 8192 * 2);
  u16* Ug  = (u16*)alloc((size_t)NCHUNKS * 8192 * 2);
  u16* Gg  = (u16*)alloc((size_t)NCHUNKS * 4096 * 2);
  u16* KTg = (u16*)alloc((size_t)NCHUNKS * 8192 * 2);
  float* beta_g = (float*)alloc((size_t)Bn * Hn * Ln * 4);
  u16* Og = vn;       // v dead after precompute
  u16* onorm = qn;    // q dead after scan

  // 0) downcast hidden_states
  hipLaunchKernelGGL(k_cvt, dim3(Mrows * Dn / 8 / 256), dim3(256), 0, stream, hs_f, hsb, Mrows * Dn / 8);

  // 1) transposes + downcast
  TransArgs ta;
  ta.src[0] = Wq; ta.dst[0] = WqT; ta.rows[0] = 2048; ta.cols[0] = 2048;
  ta.src[1] = Wk; ta.dst[1] = WkT; ta.rows[1] = 2048; ta.cols[1] = 2048;
  ta.src[2] = Wv; ta.dst[2] = WvT; ta.rows[2] = 2048; ta.cols[2] = 2048;
  ta.src[3] = Wo; ta.dst[3] = WoT; ta.rows[3] = 2048; ta.cols[3] = 2048;
  ta.src[4] = Wb; ta.dst[4] = WbT; ta.rows[4] = 2048; ta.cols[4] = 16;
  hipLaunchKernelGGL(k_trans, dim3(64, 64, 5), dim3(32, 8), 0, stream, ta);

  // 1b) beta for all heads (reads hs once)
  hipLaunchKernelGGL(k_beta, dim3(Mrows / 64), dim3(256), 0, stream, hsb, WbT, beta_g);

  // 2) fused q/k/v projection: one 4096x6144x2048 GEMM, 256x384 tiles, grid-exact 256
  {
    Gemm2Args g2;
    g2.A = hsb; g2.Bt = WqT; g2.C = qn; g2.K = 2048;
    hipLaunchKernelGGL(k_gemm2, dim3(256), dim3(512), 0, stream, g2);
  }

  // 3) l2 normalize q (with dh^-0.5) and k
  hipLaunchKernelGGL(k_l2, dim3(16384, 2), dim3(256), 0, stream, qn, kn);

  // 4) chunk precompute
  hipLaunchKernelGGL(k_pre, dim3(NCHUNKS), dim3(256), 0, stream,
                     beta_g, qn, kn, vn, W2g, Ug, Gg, KTg);

  // 5) sequential scan
  hipLaunchKernelGGL(k_scan, dim3(32, 8), dim3(256), 0, stream,
                     qn, W2g, Ug, Gg, KTg, Og);

  // 6) RMSNorm
  hipLaunchKernelGGL(k_rms, dim3(16384), dim3(256), 0, stream, Og, onw, onorm);

  // 7) output projection (fp32 out -> d_out)
  GemmArgs go;
  go.A = onorm; go.Bt = WoT; go.C = d_out; go.epi = 0;
  go.f32out = 1; go.M = Mrows; go.N = 2048; go.K = 2048;
  hipLaunchKernelGGL(k_gemm, dim3(16, 32), dim3(256), 0, stream, go);
}

// Round 4
// 488.308 us; speedup vs baseline: 1.1205x; 1.0194x over previous
//
#include <hip/hip_runtime.h>
#include <hip/hip_bf16.h>
#include <cstdint>

#define DEV static __device__ __forceinline__

typedef unsigned short u16;
typedef unsigned int u32;
typedef __attribute__((ext_vector_type(8))) short short8;
typedef __attribute__((ext_vector_type(4))) float f32x4;

constexpr int Bn = 2, Ln = 2048, Dn = 2048, Hn = 16;
constexpr int Mrows = Bn * Ln;          // 4096
constexpr int CHK = 64, NCK = Ln / CHK; // chunk=64, 32 chunks/seq
constexpr int NCHUNKS = Bn * Hn * NCK;  // 1024

DEV float b2f(u16 s) { union { float f; u32 u; } x; x.u = ((u32)s) << 16; return x.f; }
DEV u16 f2b(float f) {
  union { float f; u32 u; } x; x.f = f; u32 u = x.u;
  return (u16)((u + 0x7fffu + ((u >> 16) & 1u)) >> 16);  // RNE
}

DEV void cp16(const void* g, void* l) {
  __builtin_amdgcn_global_load_lds(
      (const __attribute__((address_space(1))) u32*)(unsigned long long)(g),
      (__attribute__((address_space(3))) u32*)(unsigned long long)(l), 16, 0, 0);
}

DEV f32x4 mfma16(short8 a, short8 b, f32x4 c) {
  return __builtin_amdgcn_mfma_f32_16x16x32_bf16(a, b, c, 0, 0, 0);
}

// ---------------- fp32 -> bf16 elementwise convert ----------------
__global__ void k_cvt(const float* __restrict__ src, u16* __restrict__ dst, int n8) {
  int i = blockIdx.x * blockDim.x + threadIdx.x;
  if (i >= n8) return;
  const float4* s4 = (const float4*)(src + (size_t)i * 8);
  float4 a = s4[0], b = s4[1];
  u16 o[8] = {f2b(a.x), f2b(a.y), f2b(a.z), f2b(a.w), f2b(b.x), f2b(b.y), f2b(b.z), f2b(b.w)};
  *(short8*)(dst + (size_t)i * 8) = *(short8*)o;
}

// ---------------- transpose + downcast (fp32 weights -> bf16 B^T form) ----------------
struct TransArgs {
  const float* src[5]; u16* dst[5]; int rows[5]; int cols[5];
};
__global__ void k_trans(TransArgs t) {
  __shared__ u16 tile[32][33];
  int z = blockIdx.z;
  const float* src = t.src[z]; u16* dst = t.dst[z];
  int rows = t.rows[z], cols = t.cols[z];
  int r0 = blockIdx.y * 32, c0 = blockIdx.x * 32;
  if (r0 >= rows || c0 >= cols) return;
  int tx = threadIdx.x, ty = threadIdx.y;
  for (int i = ty; i < 32; i += 8) {
    int r = r0 + i, c = c0 + tx;
    if (r < rows && c < cols) tile[i][tx] = f2b(src[(size_t)r * cols + c]);
  }
  __syncthreads();
  for (int i = ty; i < 32; i += 8) {
    int r = c0 + i, c = r0 + tx;
    if (r < cols && c < rows) dst[(size_t)r * rows + c] = tile[tx][i];
  }
}

// ---------------- beta = sigmoid(hs @ Wb) for all heads, MFMA GEMV ----------------
__global__ __launch_bounds__(256) void k_beta(const u16* __restrict__ hs,
                                              const u16* __restrict__ WbT,
                                              float* __restrict__ beta_g) {
  int tid = threadIdx.x, wave = tid >> 6, lane = tid & 63, quad = lane >> 4, l15 = lane & 15;
  int tok0 = blockIdx.x * 64 + wave * 16;
  const u16* arow = hs + (size_t)(tok0 + l15) * Dn;   // A[m=l15][k]
  const u16* brow = WbT + (size_t)l15 * Dn;           // B[n=head=l15][k]
  f32x4 acc = {0.f, 0.f, 0.f, 0.f};
  for (int k = 0; k < Dn; k += 32) {
    short8 af = *(const short8*)&arow[k + quad * 8];
    short8 bf = *(const short8*)&brow[k + quad * 8];
    acc = mfma16(af, bf, acc);
  }
  int b = (blockIdx.x * 64) >> 11;
  int l = (blockIdx.x * 64 + wave * 16) & 2047;
#pragma unroll
  for (int r = 0; r < 4; r++) {
    beta_g[(size_t)(b * Hn + l15) * Ln + l + quad * 4 + r] = 1.f / (1.f + __expf(-acc[r]));
  }
}

// ---------------- 128x128-tile MFMA GEMM, C = act(A @ Bt^T) ----------------
// XOR-swizzled LDS (both-sides): stage source col-block = (lane&7)^(lane>>3);
// read slot = (kk/8 + quad) ^ (l15&7). Kills the 16-way same-slot conflict.
struct GemmArgs {
  const u16* A; const u16* Bt; void* C; int epi;  // epi: 0 none, 1 silu
  int f32out;
  int M, N, K;
};
__global__ __launch_bounds__(256) void k_gemm(GemmArgs g) {
  __shared__ u16 As[128 * 64];
  __shared__ u16 Bs[128 * 64];
  const u16* A = g.A; const u16* Bt = g.Bt;
  int epi = g.epi;
  int K = g.K, N = g.N;
  int tid = threadIdx.x, wave = tid >> 6, lane = tid & 63;
  int quad = lane >> 4, l15 = lane & 15;
  int m0 = blockIdx.y * 128, n0 = blockIdx.x * 128;
  int wm = (wave >> 1) * 64, wn = (wave & 1) * 64;
  f32x4 acc[4][4];
#pragma unroll
  for (int i = 0; i < 4; i++)
#pragma unroll
    for (int j = 0; j < 4; j++) acc[i][j] = (f32x4){0.f, 0.f, 0.f, 0.f};
  int scol = ((lane & 7) ^ (lane >> 3)) * 8;  // inverse-swizzled source col-block
  const u16* Ag = A + (size_t)(m0 + wave * 32 + (lane >> 3)) * K + scol;
  const u16* Bg = Bt + (size_t)(n0 + wave * 32 + (lane >> 3)) * K + scol;
  u16* Al = &As[wave * 32 * 64];
  u16* Bl = &Bs[wave * 32 * 64];
  int sw8 = l15 & 7;
  for (int k0 = 0; k0 < K; k0 += 64) {
#pragma unroll
    for (int t = 0; t < 4; t++) {
      cp16(Ag + k0 + t * 8 * K, Al + t * 8 * 64);
      cp16(Bg + k0 + t * 8 * K, Bl + t * 8 * 64);
    }
    __syncthreads();
#pragma unroll
    for (int kk = 0; kk < 64; kk += 32) {
      int sl = (((kk >> 3) + quad) ^ sw8) * 8;  // swizzled read slot
      short8 af[4], bf[4];
#pragma unroll
      for (int i = 0; i < 4; i++) af[i] = *(const short8*)&As[(wm + i * 16 + l15) * 64 + sl];
#pragma unroll
      for (int i = 0; i < 4; i++) bf[i] = *(const short8*)&Bs[(wn + i * 16 + l15) * 64 + sl];
#pragma unroll
      for (int i = 0; i < 4; i++)
#pragma unroll
        for (int j = 0; j < 4; j++) acc[i][j] = mfma16(af[i], bf[j], acc[i][j]);
    }
    __syncthreads();
  }
#pragma unroll
  for (int i = 0; i < 4; i++)
#pragma unroll
    for (int j = 0; j < 4; j++) {
      int row = m0 + wm + i * 16 + quad * 4;
      int col = n0 + wn + j * 16 + l15;
#pragma unroll
      for (int r = 0; r < 4; r++) {
        float v = acc[i][j][r];
        if (epi == 1) v = v / (1.f + __expf(-v));  // silu
        if (g.f32out) ((float*)g.C)[(size_t)(row + r) * N + col] = v;
        else ((u16*)g.C)[(size_t)(row + r) * N + col] = f2b(v);
      }
    }
}

// ---------------- fused QKV GEMM: 256x384 tile, 4-phase unit pipeline ----------------
// A [4096][2048], Bt [6144][2048] (WqT|WkT|WvT), C base = qn (qn|kn|vn contiguous).
// Stage unit = 32 K-cols: A-unit 256x32 (16KB, 2 loads/thr), B-unit 384x32 (24KB, 3).
// Ring-3 slots per operand; vmcnt(5) per phase (2 units in flight), never 0 in loop.
// XOR swizzle (both-sides): physical 16B-slot = quad ^ ((row>>1)&3); source col
// pre-swizzled so linear global_load_lds dest lands data at the swizzled slot.
// Read positions: 4*(l15&1) + (quad^((l15>>1)&3)) -> 8 positions x 2 lanes = free.
struct Gemm2Args { const u16* A; const u16* Bt; u16* C; int K; };

__global__ __launch_bounds__(512, 2) void k_gemm2(Gemm2Args g) {
  // A slots: 3 x 16384B at 0; B slots: 3 x 24576B at 49152. Total 122880B.
  __shared__ u16 ldsbuf[61440];
  const char* LB = (const char*)ldsbuf;
  const int K = g.K, NT = K / 64;
  const size_t Kb = (size_t)K * 2;
  int tid = threadIdx.x, wave = tid >> 6, lane = tid & 63;
  int quad = lane >> 4, l15 = lane & 15;
  int wm = wave >> 2, wn = wave & 3;  // 2M x 4N wave grid; per-wave C = 128x96

  // XCD-aware swizzle (256 % 8 == 0): each XCD gets a contiguous 32-block chunk
  int bid = blockIdx.x;
  int wg = (bid & 7) * 32 + (bid >> 3);
  int by = wg >> 4, bx = wg & 15;   // 16 x 16 tiles
  int m0 = by * 256, n0f = bx * 384;

  // staging: thread covers row r0 (+128/s); source col-block inverse-swizzled
  int r0 = tid >> 2;
  int cby = (((tid & 3) ^ ((tid >> 3) & 3)) * 16);
  const char* gA = (const char*)g.A + (size_t)(m0 + r0) * Kb + cby;
  const char* gB = (const char*)g.Bt + (size_t)(n0f + r0) * Kb + cby;

  auto stageA = [&](int slot, int t, int kh) {
    const char* src = gA + (size_t)t * 128 + kh * 64;
    u16* dst = &ldsbuf[slot * 8192 + tid * 8];
    cp16(src, dst);
    cp16(src + (size_t)128 * Kb, dst + 4096);
  };
  auto stageB = [&](int slot, int t, int kh) {
    const char* src = gB + (size_t)t * 128 + kh * 64;
    u16* dst = &ldsbuf[24576 + slot * 12288 + tid * 8];
    cp16(src, dst);
    cp16(src + (size_t)128 * Kb, dst + 4096);
    cp16(src + (size_t)256 * Kb, dst + 8192);
  };

  f32x4 acc0[4][6], acc1[4][6];
#pragma unroll
  for (int i = 0; i < 4; i++)
#pragma unroll
    for (int j = 0; j < 6; j++) {
      acc0[i][j] = (f32x4){0.f, 0.f, 0.f, 0.f};
      acc1[i][j] = (f32x4){0.f, 0.f, 0.f, 0.f};
    }

  // frag byte offsets within a unit: row*64 + swizzled slot*16
  int rsw = (l15 >> 1) & 3;
  int rA = (wm * 128 + l15) * 64 + ((quad ^ rsw) * 16);  // + mq*4096 + i*1024
  int rB = (wn * 96 + l15) * 64 + ((quad ^ rsw) * 16);   // + j*1024

  // prologue: stage tile 0 (units into slots 0,0,1,1)
  stageA(0, 0, 0);
  stageB(0, 0, 0);
  stageA(1, 0, 1);
  stageB(1, 0, 1);

  short8 bf[6];
  int u0 = 0;
  for (int t = 0; t < NT; ++t) {
    int u1 = u0 + 1; if (u1 == 3) u1 = 0;
    int u2 = u1 + 1; if (u2 == 3) u2 = 0;
    bool pf = (t + 1 < NT);
    const char* aK0 = LB + u0 * 16384;
    const char* aK1 = LB + u1 * 16384;
    const char* bK0 = LB + 49152 + u0 * 24576;
    const char* bK1 = LB + 49152 + u1 * 24576;

    // ---- phase 0: (mq=0, kh=0); stage A(t+1,0) -> u2 ----
    asm volatile("s_waitcnt vmcnt(5)" ::: "memory");
    __builtin_amdgcn_s_barrier();
    __builtin_amdgcn_sched_barrier(0);
    if (pf) stageA(u2, t + 1, 0);
    {
      short8 av[4];
#pragma unroll
      for (int i = 0; i < 4; i++) av[i] = *(const short8*)(aK0 + rA + i * 1024);
#pragma unroll
      for (int j = 0; j < 6; j++) bf[j] = *(const short8*)(bK0 + rB + j * 1024);
      __builtin_amdgcn_s_setprio(1);
#pragma unroll
      for (int i = 0; i < 4; i++)
#pragma unroll
        for (int j = 0; j < 6; j++) acc0[i][j] = mfma16(av[i], bf[j], acc0[i][j]);
      __builtin_amdgcn_s_setprio(0);
    }

    // ---- phase 1: (mq=1, kh=0); stage B(t+1,0) -> u2 ----
    asm volatile("s_waitcnt vmcnt(5)" ::: "memory");
    __builtin_amdgcn_s_barrier();
    __builtin_amdgcn_sched_barrier(0);
    if (pf) stageB(u2, t + 1, 0);
    {
      short8 av[4];
#pragma unroll
      for (int i = 0; i < 4; i++) av[i] = *(const short8*)(aK0 + rA + 4096 + i * 1024);
      __builtin_amdgcn_s_setprio(1);
#pragma unroll
      for (int i = 0; i < 4; i++)
#pragma unroll
        for (int j = 0; j < 6; j++) acc1[i][j] = mfma16(av[i], bf[j], acc1[i][j]);
      __builtin_amdgcn_s_setprio(0);
    }

    // ---- phase 2: (mq=0, kh=1); stage A(t+1,1) -> u0 ----
    if (t == NT - 1) asm volatile("s_waitcnt vmcnt(0)" ::: "memory");
    else asm volatile("s_waitcnt vmcnt(5)" ::: "memory");
    __builtin_amdgcn_s_barrier();
    __builtin_amdgcn_sched_barrier(0);
    if (pf) stageA(u0, t + 1, 1);
    {
      short8 av[4];
#pragma unroll
      for (int i = 0; i < 4; i++) av[i] = *(const short8*)(aK1 + rA + i * 1024);
#pragma unroll
      for (int j = 0; j < 6; j++) bf[j] = *(const short8*)(bK1 + rB + j * 1024);
      __builtin_amdgcn_s_setprio(1);
#pragma unroll
      for (int i = 0; i < 4; i++)
#pragma unroll
        for (int j = 0; j < 6; j++) acc0[i][j] = mfma16(av[i], bf[j], acc0[i][j]);
      __builtin_amdgcn_s_setprio(0);
    }

    // ---- phase 3: (mq=1, kh=1); stage B(t+1,1) -> u0 ----
    asm volatile("s_waitcnt vmcnt(5)" ::: "memory");
    __builtin_amdgcn_s_barrier();
    __builtin_amdgcn_sched_barrier(0);
    if (pf) stageB(u0, t + 1, 1);
    {
      short8 av[4];
#pragma unroll
      for (int i = 0; i < 4; i++) av[i] = *(const short8*)(aK1 + rA + 4096 + i * 1024);
      __builtin_amdgcn_s_setprio(1);
#pragma unroll
      for (int i = 0; i < 4; i++)
#pragma unroll
        for (int j = 0; j < 6; j++) acc1[i][j] = mfma16(av[i], bf[j], acc1[i][j]);
      __builtin_amdgcn_s_setprio(0);
    }

    u0 = u2;
  }

  // epilogue: per-fragment z selection across the q/k/v boundary
#pragma unroll
  for (int mq = 0; mq < 2; mq++) {
#pragma unroll
    for (int i = 0; i < 4; i++)
#pragma unroll
      for (int j = 0; j < 6; j++) {
        f32x4 a = mq ? acc1[i][j] : acc0[i][j];
        int row = m0 + wm * 128 + mq * 64 + i * 16 + quad * 4;
        int colg = n0f + wn * 96 + j * 16;
        int z = colg >> 11;
        u16* Cz = g.C + (size_t)z * ((size_t)Mrows * 2048);
        int col = (colg & 2047) + l15;
#pragma unroll
        for (int r = 0; r < 4; r++) {
          float v = a[r];
          if (z == 2) v = v / (1.f + __expf(-v));  // silu (v-projection)
          Cz[(size_t)(row + r) * 2048 + col] = f2b(v);
        }
      }
  }
}

// ---------------- l2-normalize q,k rows of 128 (in place, bf16) ----------------
__global__ void k_l2(u16* qn, u16* kn) {
  int tid = threadIdx.x, wave = tid >> 6, lane = tid & 63;
  size_t row = (size_t)blockIdx.x * 4 + wave;  // (b*L+l)*16+h
  u16* p = (blockIdx.y ? kn : qn) + row * 128;
  u32 u = *(const u32*)&p[lane * 2];
  float x0 = b2f((u16)(u & 0xffff)), x1 = b2f((u16)(u >> 16));
  float ss = x0 * x0 + x1 * x1;
#pragma unroll
  for (int o = 32; o > 0; o >>= 1) ss += __shfl_xor(ss, o, 64);
  float sc = 1.f / fmaxf(sqrtf(ss), 1e-12f);
  if (blockIdx.y == 0) sc *= 0.08838834764831845f;  // dh^-0.5
  u32 outv = (u32)f2b(x0 * sc) | ((u32)f2b(x1 * sc) << 16);
  *(u32*)&p[lane * 2] = outv;
}

// ---------------- per-chunk precompute: Minv (Neumann), W2,U,G,KT ----------------
// ST=72: row stride 36 dwords (== 4 mod 32) puts ds_read_b128 fragment reads at
// the bank floor (8 lanes per 4-bank group). ST=80 (== 8 mod 32) was 2x floor.
constexpr int ST = 72;
// 4 LDS buffers (Br, Bc, M0, M1): T = B^2 staged through registers and written
// IN PLACE into Br/Bc -> LDS 61952 -> 37120 B -> 4 blocks/CU (was 2).
__global__ __launch_bounds__(256, 4) void k_pre(
    const float* __restrict__ beta_g,
    const u16* __restrict__ qn, const u16* __restrict__ kn, const u16* __restrict__ vn,
    u16* __restrict__ W2g, u16* __restrict__ Ug, u16* __restrict__ Gg, u16* __restrict__ KTg) {
  __shared__ float beta_s[64];
  __shared__ u16 mats[4 * 64 * ST];
  int gid = blockIdx.x;
  int c = gid & 31, h = (gid >> 5) & 15, b = gid >> 9;
  int tid = threadIdx.x;
  int l0 = c * 64;

  if (tid < 64) beta_s[tid] = beta_g[(size_t)(b * Hn + h) * Ln + l0 + tid];
  __syncthreads();

  int wave = tid >> 6, lane = tid & 63, quad = lane >> 4, l15 = lane & 15;
  u16 *Br = mats, *Bc = mats + 64 * ST, *M0 = mats + 2 * 64 * ST, *M1 = mats + 3 * 64 * ST;

  // P1: A_full = K K^T (MFMA), G = tril(Q K^T); build B=-strict_tril(diag(beta)A), M=I+B
  {
    const u16* krowB = kn + (size_t)(b * Ln + l0 + wave * 16 + l15) * Dn + h * 128;
    short8 bfr[4];
#pragma unroll
    for (int s = 0; s < 4; s++) bfr[s] = *(const short8*)&krowB[quad * 8 + 32 * s];
#pragma unroll
    for (int mt = 0; mt < 4; ++mt) {
      const u16* arow_k = kn + (size_t)(b * Ln + l0 + mt * 16 + l15) * Dn + h * 128;
      const u16* arow_q = qn + (size_t)(b * Ln + l0 + mt * 16 + l15) * Dn + h * 128;
      f32x4 accA = {0.f, 0.f, 0.f, 0.f}, accG = {0.f, 0.f, 0.f, 0.f};
#pragma unroll
      for (int s = 0; s < 4; s++) {
        short8 ak = *(const short8*)&arow_k[quad * 8 + 32 * s];
        short8 aq = *(const short8*)&arow_q[quad * 8 + 32 * s];
        accA = mfma16(ak, bfr[s], accA);
        accG = mfma16(aq, bfr[s], accG);
      }
      int t = wave * 16 + l15;
#pragma unroll
      for (int r = 0; r < 4; r++) {
        int i = mt * 16 + quad * 4 + r;
        u16 nb = f2b((t < i) ? -beta_s[i] * accA[r] : 0.f);
        Br[i * ST + t] = nb;
        Bc[t * ST + i] = nb;
        M0[i * ST + t] = (t == i) ? f2b(1.f) : nb;
        Gg[(size_t)gid * 4096 + (size_t)i * 64 + t] = f2b((t <= i) ? accG[r] : 0.f);
      }
    }
  }
  __syncthreads();

  // P2: Minv = (I+B)(I+B^2)(I+B^4)(I+B^8)(I+B^16)(I+B^32)
  u16 *Mc = M0, *Mn = M1;
#pragma unroll
  for (int it = 0; it < 5; ++it) {
    const int tT = (it < 3) ? 0 : ((it == 3) ? 1 : 2);
    const int tI = (it < 4) ? 0 : 1;
    short8 bb[2];
#pragma unroll
    for (int s = 0; s < 2; s++) bb[s] = *(const short8*)&Bc[(wave * 16 + l15) * ST + quad * 8 + 32 * s];
    f32x4 accT[4];
#pragma unroll
    for (int mt = 0; mt < 4; mt++) {
      accT[mt] = (f32x4){0.f, 0.f, 0.f, 0.f};
      if (mt - wave >= tT) {
#pragma unroll
        for (int s = 0; s < 2; s++) {
          short8 af = *(const short8*)&Br[(mt * 16 + l15) * ST + quad * 8 + 32 * s];
          accT[mt] = mfma16(af, bb[s], accT[mt]);
        }
      }
    }
    __syncthreads();  // all lanes done reading Br/Bc -> safe to overwrite
#pragma unroll
    for (int mt = 0; mt < 4; mt++) {
      if (mt - wave >= tI) {
#pragma unroll
        for (int r = 0; r < 4; r++) {
          int i = mt * 16 + quad * 4 + r, t = wave * 16 + l15;
          u16 v = f2b(accT[mt][r]);
          Br[i * ST + t] = v;
          Bc[t * ST + i] = v;
        }
      }
    }
    __syncthreads();  // T visible
    short8 tb[2];
#pragma unroll
    for (int s = 0; s < 2; s++) tb[s] = *(const short8*)&Bc[(wave * 16 + l15) * ST + quad * 8 + 32 * s];
#pragma unroll
    for (int mt = 0; mt < 4; mt++) {
      if (mt - wave >= tT) {
        f32x4 a;
#pragma unroll
        for (int r = 0; r < 4; r++) a[r] = b2f(Mc[(mt * 16 + quad * 4 + r) * ST + wave * 16 + l15]);
#pragma unroll
        for (int s = 0; s < 2; s++) {
          short8 af = *(const short8*)&Mc[(mt * 16 + l15) * ST + quad * 8 + 32 * s];
          a = mfma16(af, tb[s], a);
        }
#pragma unroll
        for (int r = 0; r < 4; r++) Mn[(mt * 16 + quad * 4 + r) * ST + wave * 16 + l15] = f2b(a[r]);
      } else {
#pragma unroll
        for (int r = 0; r < 4; r++)
          Mn[(mt * 16 + quad * 4 + r) * ST + wave * 16 + l15] =
              Mc[(mt * 16 + quad * 4 + r) * ST + wave * 16 + l15];
      }
    }
    u16* tmp = Mc; Mc = Mn; Mn = tmp;
  }
  __syncthreads();  // drain last M-update before XT reuses Br/Bc

  // P3: W2 = Minv (beta.K), U = Minv (beta.V); also KT (unscaled) to global
  u16* XT = mats;  // scratch slots 0-1 (Br,Bc); Mc lives in slot 3 after 5 swaps
  for (int pass = 0; pass < 2; ++pass) {
    const u16* src = pass ? vn : kn;
    for (int idx = tid; idx < 64 * 128; idx += 256) {
      int t = idx >> 7, dk = idx & 127;
      float v = b2f(src[(size_t)(b * Ln + l0 + t) * Dn + h * 128 + dk]);
      XT[dk * ST + t] = f2b(v * beta_s[t]);
      if (pass == 0) KTg[(size_t)gid * 8192 + (size_t)dk * 64 + t] = f2b(v);
    }
    __syncthreads();
    u16* dst = pass ? Ug : W2g;
#pragma unroll
    for (int half = 0; half < 2; ++half) {
      int nt = wave + half * 4;
      short8 bx[2];
#pragma unroll
      for (int s = 0; s < 2; s++) bx[s] = *(const short8*)&XT[(nt * 16 + l15) * ST + quad * 8 + 32 * s];
#pragma unroll
      for (int mt = 0; mt < 4; mt++) {
        f32x4 a = {0.f, 0.f, 0.f, 0.f};
#pragma unroll
        for (int s = 0; s < 2; s++) {
          short8 af = *(const short8*)&Mc[(mt * 16 + l15) * ST + quad * 8 + 32 * s];
          a = mfma16(af, bx[s], a);
        }
#pragma unroll
        for (int r = 0; r < 4; r++)
          dst[(size_t)gid * 8192 + (size_t)(mt * 16 + quad * 4 + r) * 128 + nt * 16 + l15] = f2b(a[r]);
      }
    }
    __syncthreads();
  }
}

// ---------------- sequential chunk scan (per b,h and 16-wide v-slice) ----------------
struct Frg { short8 w2[4], qf[4], gf[2], k0[2], k1[2]; float u[4]; };

__global__ __launch_bounds__(256) void k_scan(
    const u16* __restrict__ qn, const u16* __restrict__ W2g, const u16* __restrict__ Ug,
    const u16* __restrict__ Gg, const u16* __restrict__ KTg, u16* __restrict__ Og) {
  constexpr int SST = 136, DST = 104;
  __shared__ u16 Sb[16 * SST];  // S^T slice, bf16 shadow: [v][dk]
  __shared__ u16 Db[16 * DST];  // Delta^T slice: [v][t]
  int bh = blockIdx.x, sl = blockIdx.y;
  int b = bh >> 4, h = bh & 15, c0 = sl * 16;
  int tid = threadIdx.x, wave = tid >> 6, lane = tid & 63, quad = lane >> 4, l15 = lane & 15;
  for (int i = tid; i < 16 * SST; i += 256) Sb[i] = 0;
  f32x4 accS0 = {0.f, 0.f, 0.f, 0.f}, accS1 = {0.f, 0.f, 0.f, 0.f};  // fp32 master state
  __syncthreads();

  auto load_frags = [&](Frg& F, int ci) {
    size_t ck = (size_t)bh * NCK + ci;
    const u16* w2row = W2g + ck * 8192 + (size_t)(wave * 16 + l15) * 128;
    const u16* qrow = qn + (size_t)(b * Ln + ci * 64 + wave * 16 + l15) * Dn + h * 128;
#pragma unroll
    for (int s = 0; s < 4; s++) {
      F.w2[s] = *(const short8*)&w2row[quad * 8 + 32 * s];
      F.qf[s] = *(const short8*)&qrow[quad * 8 + 32 * s];
    }
    const u16* grow = Gg + ck * 4096 + (size_t)(wave * 16 + l15) * 64;
    const u16* kt0 = KTg + ck * 8192 + (size_t)(wave * 16 + l15) * 64;
    const u16* kt1 = KTg + ck * 8192 + (size_t)((wave + 4) * 16 + l15) * 64;
#pragma unroll
    for (int s = 0; s < 2; s++) {
      F.gf[s] = *(const short8*)&grow[quad * 8 + 32 * s];
      F.k0[s] = *(const short8*)&kt0[quad * 8 + 32 * s];
      F.k1[s] = *(const short8*)&kt1[quad * 8 + 32 * s];
    }
    const u16* urow = Ug + ck * 8192 + (size_t)(wave * 16 + quad * 4) * 128 + c0 + l15;
#pragma unroll
    for (int r = 0; r < 4; r++) F.u[r] = b2f(urow[(size_t)r * 128]);
  };

  auto compute = [&](const Frg& F, int ci) {
    f32x4 accT = {0.f, 0.f, 0.f, 0.f}, accO = {0.f, 0.f, 0.f, 0.f};
#pragma unroll
    for (int s = 0; s < 4; s++) {
      short8 sf = *(const short8*)&Sb[l15 * SST + quad * 8 + 32 * s];
      accT = mfma16(F.w2[s], sf, accT);   // W2 @ S0
      accO = mfma16(F.qf[s], sf, accO);   // Q @ S0
    }
#pragma unroll
    for (int r = 0; r < 4; r++) {
      float d = F.u[r] - accT[r];         // Delta = U - W2@S0
      Db[l15 * DST + wave * 16 + quad * 4 + r] = f2b(d);
    }
    __syncthreads();
#pragma unroll
    for (int s = 0; s < 2; s++) {
      short8 df = *(const short8*)&Db[l15 * DST + quad * 8 + 32 * s];
      accO = mfma16(F.gf[s], df, accO);   // O += tril(QK^T) @ Delta
      accS0 = mfma16(F.k0[s], df, accS0); // S += K^T @ Delta
      accS1 = mfma16(F.k1[s], df, accS1);
    }
    u16* orow = Og + (size_t)(b * Ln + ci * 64 + wave * 16 + quad * 4) * Dn + h * 128 + c0 + l15;
#pragma unroll
    for (int r = 0; r < 4; r++) orow[(size_t)r * Dn] = f2b(accO[r]);
#pragma unroll
    for (int r = 0; r < 4; r++) {
      Sb[l15 * SST + wave * 16 + quad * 4 + r] = f2b(accS0[r]);
      Sb[l15 * SST + (wave + 4) * 16 + quad * 4 + r] = f2b(accS1[r]);
    }
    __syncthreads();
  };

  Frg FA, FB;
  load_frags(FA, 0);
  for (int ci = 0; ci < NCK; ci += 2) {
    load_frags(FB, ci + 1);
    compute(FA, ci);
    if (ci + 2 < NCK) load_frags(FA, ci + 2);
    compute(FB, ci + 1);
  }
}

// ---------------- RMSNorm over head dim (fp32 weight) ----------------
__global__ void k_rms(const u16* __restrict__ Og, const float* __restrict__ w, u16* __restrict__ out) {
  int tid = threadIdx.x, wave = tid >> 6, lane = tid & 63;
  size_t row = (size_t)blockIdx.x * 4 + wave;
  const u16* p = Og + row * 128;
  u32 u = *(const u32*)&p[lane * 2];
  float x0 = b2f((u16)(u & 0xffff)), x1 = b2f((u16)(u >> 16));
  float ss = x0 * x0 + x1 * x1;
#pragma unroll
  for (int o = 32; o > 0; o >>= 1) ss += __shfl_xor(ss, o, 64);
  float sc = rsqrtf(ss * (1.f / 128.f) + 1e-5f);
  float w0 = w[lane * 2], w1 = w[lane * 2 + 1];
  u32 o2 = (u32)f2b(x0 * sc * w0) | ((u32)f2b(x1 * sc * w1) << 16);
  *(u32*)&out[row * 128 + lane * 2] = o2;
}

// ---------------- host ----------------
extern "C" void kernel_launch(void* const* d_in, const int* in_sizes, int n_in,
                              void* d_out, int out_size, void* d_ws, size_t ws_size,
                              hipStream_t stream) {
  (void)in_sizes; (void)n_in; (void)out_size; (void)ws_size;
  const float* hs_f = (const float*)d_in[0];
  const float* Wq = (const float*)d_in[1];
  const float* Wk = (const float*)d_in[2];
  const float* Wv = (const float*)d_in[3];
  const float* Wb = (const float*)d_in[4];
  const float* onw = (const float*)d_in[5];
  const float* Wo = (const float*)d_in[6];

  char* ws = (char*)d_ws;
  size_t off = 0;
  auto alloc = [&](size_t bytes) -> void* {
    void* p = ws + off;
    off += (bytes + 255) & ~(size_t)255;
    return p;
  };
  const size_t WB = (size_t)2048 * 2048 * 2;
  const size_t XB = (size_t)4096 * 2048 * 2;
  u16* WqT = (u16*)alloc(WB);   // WqT|WkT|WvT contiguous => fused Bt [6144][2048]
  u16* WkT = (u16*)alloc(WB);
  u16* WvT = (u16*)alloc(WB);
  u16* WoT = (u16*)alloc(WB);
  u16* WbT = (u16*)alloc((size_t)16 * 2048 * 2);
  u16* hsb = (u16*)alloc(XB);
  u16* qn  = (u16*)alloc(XB);   // qn|kn|vn contiguous => fused C
  u16* kn  = (u16*)alloc(XB);
  u16* vn  = (u16*)alloc(XB);   // reused as O after precompute
  u16* W2g = (u16*)alloc((size_t)NCHUNKS * 8192 * 2);
  u16* Ug  = (u16*)alloc((size_t)NCHUNKS * 8192 * 2);
  u16* Gg  = (u16*)alloc((size_t)NCHUNKS * 4096 * 2);
  u16* KTg = (u16*)alloc((size_t)NCHUNKS * 8192 * 2);
  float* beta_g = (float*)alloc((size_t)Bn * Hn * Ln * 4);
  u16* Og = vn;       // v dead after precompute
  u16* onorm = qn;    // q dead after scan

  // 0) downcast hidden_states
  hipLaunchKernelGGL(k_cvt, dim3(Mrows * Dn / 8 / 256), dim3(256), 0, stream, hs_f, hsb, Mrows * Dn / 8);

  // 1) transposes + downcast
  TransArgs ta;
  ta.src[0] = Wq; ta.dst[0] = WqT; ta.rows[0] = 2048; ta.cols[0] = 2048;
  ta.src[1] = Wk; ta.dst[1] = WkT; ta.rows[1] = 2048; ta.cols[1] = 2048;
  ta.src[2] = Wv; ta.dst[2] = WvT; ta.rows[2] = 2048; ta.cols[2] = 2048;
  ta.src[3] = Wo; ta.dst[3] = WoT; ta.rows[3] = 2048; ta.cols[3] = 2048;
  ta.src[4] = Wb; ta.dst[4] = WbT; ta.rows[4] = 2048; ta.cols[4] = 16;
  hipLaunchKernelGGL(k_trans, dim3(64, 64, 5), dim3(32, 8), 0, stream, ta);

  // 1b) beta for all heads (reads hs once)
  hipLaunchKernelGGL(k_beta, dim3(Mrows / 64), dim3(256), 0, stream, hsb, WbT, beta_g);

  // 2) fused q/k/v projection: one 4096x6144x2048 GEMM, 256x384 tiles, grid-exact 256
  {
    Gemm2Args g2;
    g2.A = hsb; g2.Bt = WqT; g2.C = qn; g2.K = 2048;
    hipLaunchKernelGGL(k_gemm2, dim3(256), dim3(512), 0, stream, g2);
  }

  // 3) l2 normalize q (with dh^-0.5) and k
  hipLaunchKernelGGL(k_l2, dim3(16384, 2), dim3(256), 0, stream, qn, kn);

  // 4) chunk precompute
  hipLaunchKernelGGL(k_pre, dim3(NCHUNKS), dim3(256), 0, stream,
                     beta_g, qn, kn, vn, W2g, Ug, Gg, KTg);

  // 5) sequential scan
  hipLaunchKernelGGL(k_scan, dim3(32, 8), dim3(256), 0, stream,
                     qn, W2g, Ug, Gg, KTg, Og);

  // 6) RMSNorm
  hipLaunchKernelGGL(k_rms, dim3(16384), dim3(256), 0, stream, Og, onw, onorm);

  // 7) output projection (fp32 out -> d_out)
  GemmArgs go;
  go.A = onorm; go.Bt = WoT; go.C = d_out; go.epi = 0;
  go.f32out = 1; go.M = Mrows; go.N = 2048; go.K = 2048;
  hipLaunchKernelGGL(k_gemm, dim3(16, 32), dim3(256), 0, stream, go);
}